// Round 6
// baseline (1100.060 us; speedup 1.0000x reference)
//
#include <hip/hip_runtime.h>

#define N_NODES  50000
#define N_EDGES  800000
#define N_GRAPHS 64

typedef unsigned short u16x8 __attribute__((ext_vector_type(8)));

__device__ __forceinline__ float bf2f(unsigned short h) {
    return __uint_as_float((unsigned)h << 16);
}
__device__ __forceinline__ unsigned short f2bf(float f) {
    unsigned u = __float_as_uint(f);
    unsigned r = (u + 0x7FFFu + ((u >> 16) & 1u)) >> 16;   // RNE
    return (unsigned short)r;
}

// ---------------- utility kernels ----------------

__global__ void zero_int_kernel(int* __restrict__ p, int n) {
    for (int i = blockIdx.x * blockDim.x + threadIdx.x; i < n; i += gridDim.x * blockDim.x)
        p[i] = 0;
}

// in-degree histogram (int)
__global__ void hist_kernel(const int* __restrict__ ei, int* __restrict__ cnt) {
    const int* dst = ei + N_EDGES;
    for (int e = blockIdx.x * blockDim.x + threadIdx.x; e < N_EDGES; e += gridDim.x * blockDim.x)
        atomicAdd(&cnt[dst[e]], 1);
}

__global__ void dinv_kernel(const int* __restrict__ cnt, float* __restrict__ dinv) {
    for (int i = blockIdx.x * blockDim.x + threadIdx.x; i < N_NODES; i += gridDim.x * blockDim.x)
        dinv[i] = rsqrtf((float)cnt[i] + 1.f);   // +1 self-loop
}

// single-block exclusive scan of cnt -> rowptr; also resets cnt to 0 (fill counters)
__global__ __launch_bounds__(1024) void scan_kernel(int* __restrict__ cnt, int* __restrict__ rowptr) {
    __shared__ int part[1024];
    const int CH = 49;                      // 1024*49 = 50176 >= N_NODES
    int t = threadIdx.x;
    int base = t * CH;
    int s = 0;
    for (int i = 0; i < CH; ++i) {
        int idx = base + i;
        if (idx < N_NODES) s += cnt[idx];
    }
    part[t] = s;
    __syncthreads();
    for (int off = 1; off < 1024; off <<= 1) {
        int v = (t >= off) ? part[t - off] : 0;
        __syncthreads();
        part[t] += v;
        __syncthreads();
    }
    int run = (t == 0) ? 0 : part[t - 1];
    for (int i = 0; i < CH; ++i) {
        int idx = base + i;
        if (idx < N_NODES) {
            int c = cnt[idx];
            rowptr[idx] = run;
            run += c;
            cnt[idx] = 0;                   // reset for fill pass
        }
    }
    if (t == 1023) rowptr[N_NODES] = run;
}

// place edges into CSR slots; pack (src, weight) as int2
__global__ void fill_kernel(const int* __restrict__ ei, const int* __restrict__ rowptr,
                            int* __restrict__ fill, const float* __restrict__ dinv,
                            int2* __restrict__ csr) {
    const int* src = ei;
    const int* dst = ei + N_EDGES;
    for (int e = blockIdx.x * blockDim.x + threadIdx.x; e < N_EDGES; e += gridDim.x * blockDim.x) {
        int s = src[e], d = dst[e];
        int pos = rowptr[d] + atomicAdd(&fill[d], 1);
        csr[pos] = make_int2(s, __float_as_int(dinv[s] * dinv[d]));
    }
}

// nodes-per-graph histogram (float)
__global__ void gcount_kernel(const int* __restrict__ batch, float* __restrict__ cntg) {
    for (int i = blockIdx.x * blockDim.x + threadIdx.x; i < N_NODES; i += gridDim.x * blockDim.x)
        atomicAdd(&cntg[batch[i]], 1.f);
}

// ---------------- GEMM: C[M,128] = A[M,K] @ B[K,128], fp32 math, bf16 out ----------------
template<int K>
__global__ __launch_bounds__(256) void gemm_n128(const float* __restrict__ A,
                                                 const float* __restrict__ B,
                                                 unsigned short* __restrict__ C, int M) {
    constexpr int BK = 16;
    __shared__ float As[BK][68];
    __shared__ float Bs[BK][132];

    const int tid = threadIdx.x;
    const int tx  = tid & 31;
    const int ty  = tid >> 5;
    const int row0 = blockIdx.x * 64;

    const int lar = tid >> 2;
    const int lak = (tid & 3) * 4;
    const int lbk = tid >> 4;
    const int lbc = (tid & 15) * 8;

    float acc[8][4];
    #pragma unroll
    for (int i = 0; i < 8; ++i)
        #pragma unroll
        for (int j = 0; j < 4; ++j) acc[i][j] = 0.f;

    int arow = row0 + lar;
    if (arow >= M) arow = M - 1;
    const float* Aptr = A + (long)arow * K + lak;
    const float* Bptr = B + (long)lbk * 128 + lbc;

    for (int k0 = 0; k0 < K; k0 += BK) {
        float4 av = *(const float4*)(Aptr + k0);
        As[lak + 0][lar] = av.x;
        As[lak + 1][lar] = av.y;
        As[lak + 2][lar] = av.z;
        As[lak + 3][lar] = av.w;
        float4 bv0 = *(const float4*)(Bptr + (long)k0 * 128);
        float4 bv1 = *(const float4*)(Bptr + (long)k0 * 128 + 4);
        *(float4*)&Bs[lbk][lbc]     = bv0;
        *(float4*)&Bs[lbk][lbc + 4] = bv1;
        __syncthreads();
        #pragma unroll
        for (int kk = 0; kk < BK; ++kk) {
            float4 b4 = *(const float4*)&Bs[kk][tx * 4];
            float4 a0 = *(const float4*)&As[kk][ty * 8];
            float4 a1 = *(const float4*)&As[kk][ty * 8 + 4];
            float a[8] = {a0.x, a0.y, a0.z, a0.w, a1.x, a1.y, a1.z, a1.w};
            float b[4] = {b4.x, b4.y, b4.z, b4.w};
            #pragma unroll
            for (int i = 0; i < 8; ++i)
                #pragma unroll
                for (int j = 0; j < 4; ++j)
                    acc[i][j] = fmaf(a[i], b[j], acc[i][j]);
        }
        __syncthreads();
    }

    #pragma unroll
    for (int i = 0; i < 8; ++i) {
        int r = row0 + ty * 8 + i;
        if (r < M) {
            ushort4 v;
            v.x = f2bf(acc[i][0]); v.y = f2bf(acc[i][1]);
            v.z = f2bf(acc[i][2]); v.w = f2bf(acc[i][3]);
            *(ushort4*)(C + (long)r * 128 + tx * 4) = v;
        }
    }
}

// ---------------- CSR gather (bf16 rows): persistent waves, low-VGPR ----------------
// Lane layout: es = lane>>4 (edge slot 0..3), cl = lane&15 (8 channels per lane).
// A/B unroll -> 8 rows in flight; acc = 16 fp32/lane; target VGPR <= 64 so
// 8 waves/EU stay resident (launch_bounds enforces).
// MODE 0: out[node] = relu(agg + bias)  (fp32, feeds GEMM2)
// MODE 1: z = dot(relu(agg + bias), Wl); zsum[batch[node]] += z
#define GATHER_BLOCKS 2048
template<int MODE>
__global__ __launch_bounds__(256, 8) void gather_kernel(
        const unsigned short* __restrict__ xl, const float* __restrict__ dinv,
        const int* __restrict__ rowptr, const int2* __restrict__ csr,
        const float* __restrict__ bias, float* __restrict__ outbuf,
        const float* __restrict__ Wl, const int* __restrict__ batch,
        float* __restrict__ zsum) {
    const int lane = threadIdx.x & 63;
    const int es = lane >> 4;      // edge slot 0..3
    const int cl = lane & 15;      // channel lane
    const int c0 = cl * 8;         // 8 channels per lane

    const int wave   = blockIdx.x * 4 + (threadIdx.x >> 6);
    const int nwaves = GATHER_BLOCKS * 4;

    int node = wave;
    if (node >= N_NODES) return;
    int start = rowptr[node];
    int end   = rowptr[node + 1];

    for (; node < N_NODES; ) {
        // prefetch next node's metadata (overlaps with this node's work)
        int nxt = node + nwaves;
        int n_start = 0, n_end = 0;
        if (nxt < N_NODES) {
            n_start = rowptr[nxt];
            n_end   = rowptr[nxt + 1];
        }

        // self-loop row (issue early; independent of loop)
        u16x8 sv = *(const u16x8*)(xl + (long)node * 128 + c0);

        float accA[8], accB[8];
        #pragma unroll
        for (int j = 0; j < 8; ++j) { accA[j] = 0.f; accB[j] = 0.f; }

        for (int eb = start; eb < end; eb += 8) {
            int eA = eb + es;
            int eB = eA + 4;
            int eAc = (eA < end) ? eA : start;
            int eBc = (eB < end) ? eB : start;
            int2 cA = csr[eAc];
            int2 cB = csr[eBc];
            float wA = (eA < end) ? __int_as_float(cA.y) : 0.f;
            float wB = (eB < end) ? __int_as_float(cB.y) : 0.f;
            u16x8 a0 = *(const u16x8*)(xl + (long)cA.x * 128 + c0);
            u16x8 b0 = *(const u16x8*)(xl + (long)cB.x * 128 + c0);
            #pragma unroll
            for (int j = 0; j < 8; ++j) {
                accA[j] = fmaf(wA, bf2f(a0[j]), accA[j]);
                accB[j] = fmaf(wB, bf2f(b0[j]), accB[j]);
            }
        }

        float s[8];
        #pragma unroll
        for (int j = 0; j < 8; ++j) s[j] = accA[j] + accB[j];

        // reduce across the 4 edge slots (lane bits 4,5)
        #pragma unroll
        for (int j = 0; j < 8; ++j) {
            s[j] += __shfl_xor(s[j], 16);
            s[j] += __shfl_xor(s[j], 32);
        }

        // self-loop + bias + relu (identical on all es lanes); bias loaded per
        // node in the epilogue (L1-hot) to keep loop VGPR pressure low
        float di = dinv[node];
        float w2 = di * di;
        const float4 bb0 = *(const float4*)(bias + c0);
        const float4 bb1 = *(const float4*)(bias + c0 + 4);
        float bv[8] = {bb0.x, bb0.y, bb0.z, bb0.w, bb1.x, bb1.y, bb1.z, bb1.w};
        #pragma unroll
        for (int j = 0; j < 8; ++j)
            s[j] = fmaxf(fmaf(w2, bf2f(sv[j]), s[j]) + bv[j], 0.f);

        if (MODE == 0) {
            if (es == 0) {
                float* op = outbuf + (long)node * 128 + c0;
                *(float4*)(op)     = make_float4(s[0], s[1], s[2], s[3]);
                *(float4*)(op + 4) = make_float4(s[4], s[5], s[6], s[7]);
            }
        } else {
            const float4 wl0 = *(const float4*)(Wl + c0);
            const float4 wl1 = *(const float4*)(Wl + c0 + 4);
            float z = s[0]*wl0.x + s[1]*wl0.y + s[2]*wl0.z + s[3]*wl0.w
                    + s[4]*wl1.x + s[5]*wl1.y + s[6]*wl1.z + s[7]*wl1.w;
            // sum across the 16 channel lanes (bits 0..3)
            z += __shfl_xor(z, 1);
            z += __shfl_xor(z, 2);
            z += __shfl_xor(z, 4);
            z += __shfl_xor(z, 8);
            if (lane == 0)
                atomicAdd(&zsum[batch[node]], z);
        }

        node = nxt;
        start = n_start;
        end = n_end;
    }
}

__global__ void out_kernel(const float* __restrict__ zsum, const float* __restrict__ cntg,
                           const float* __restrict__ bl, float* __restrict__ out) {
    int g = threadIdx.x;
    if (g < N_GRAPHS) out[g] = zsum[g] / fmaxf(cntg[g], 1.f) + bl[0];
}

// ---------------- launch ----------------

extern "C" void kernel_launch(void* const* d_in, const int* in_sizes, int n_in,
                              void* d_out, int out_size, void* d_ws, size_t ws_size,
                              hipStream_t stream) {
    const float* x    = (const float*)d_in[0];
    const int*   ei   = (const int*)d_in[1];
    const int*   batch= (const int*)d_in[2];
    const float* W1   = (const float*)d_in[3];
    const float* b1   = (const float*)d_in[4];
    const float* W2   = (const float*)d_in[5];
    const float* b2   = (const float*)d_in[6];
    const float* Wl   = (const float*)d_in[7];
    const float* bl   = (const float*)d_in[8];
    float* out = (float*)d_out;

    // workspace layout (4B words)
    float* ws      = (float*)d_ws;
    float* dinv    = ws;                         // 50176
    float* zsum    = ws + 50176;                 // 64
    float* cntg    = ws + 50176 + 64;            // 64
    int*   cnt_i   = (int*)(ws + 50304);         // 50176 (also fill counters)
    int*   rowptr  = (int*)(ws + 100480);        // 50176 (50001 used)
    int2*  csr     = (int2*)(ws + 150656);       // 800000 int2
    unsigned short* xl16 = (unsigned short*)(ws + 1750656);  // 6.4M bf16 (12.8 MB)
    float* h1      = ws + 1750656 + 3200000;     // 6.4M fp32 (GEMM2 input)

    // zero zsum, cntg, cnt_i in one pass (contiguous)
    zero_int_kernel<<<128, 256, 0, stream>>>((int*)(ws + 50176), 128 + 50176);

    hist_kernel<<<1024, 256, 0, stream>>>(ei, cnt_i);
    dinv_kernel<<<128, 256, 0, stream>>>(cnt_i, dinv);
    scan_kernel<<<1, 1024, 0, stream>>>(cnt_i, rowptr);
    fill_kernel<<<1024, 256, 0, stream>>>(ei, rowptr, cnt_i, dinv, csr);
    gcount_kernel<<<256, 256, 0, stream>>>(batch, cntg);

    // layer 1
    gemm_n128<768><<<782, 256, 0, stream>>>(x, W1, xl16, N_NODES);
    gather_kernel<0><<<GATHER_BLOCKS, 256, 0, stream>>>(xl16, dinv, rowptr, csr,
                                                b1, h1, nullptr, nullptr, nullptr);
    // layer 2 + pool
    gemm_n128<128><<<782, 256, 0, stream>>>(h1, W2, xl16, N_NODES);
    gather_kernel<1><<<GATHER_BLOCKS, 256, 0, stream>>>(xl16, dinv, rowptr, csr,
                                                b2, nullptr, Wl, batch, zsum);

    out_kernel<<<1, 64, 0, stream>>>(zsum, cntg, bl, out);
}

// Round 7
// 939.208 us; speedup vs baseline: 1.1713x; 1.1713x over previous
//
#include <hip/hip_runtime.h>

#define N_NODES  50000
#define N_EDGES  800000
#define N_GRAPHS 64
#define N_CHUNK  4          // 128 channels / 32
#define ZREP     16         // zsum replicas

typedef unsigned short u16x8 __attribute__((ext_vector_type(8)));

__device__ __forceinline__ float bf2f(unsigned short h) {
    return __uint_as_float((unsigned)h << 16);
}
__device__ __forceinline__ unsigned short f2bf(float f) {
    unsigned u = __float_as_uint(f);
    unsigned r = (u + 0x7FFFu + ((u >> 16) & 1u)) >> 16;   // RNE
    return (unsigned short)r;
}

// ---------------- utility kernels ----------------

__global__ void zero_int_kernel(int* __restrict__ p, int n) {
    for (int i = blockIdx.x * blockDim.x + threadIdx.x; i < n; i += gridDim.x * blockDim.x)
        p[i] = 0;
}

__global__ void hist_kernel(const int* __restrict__ ei, int* __restrict__ cnt) {
    const int* dst = ei + N_EDGES;
    for (int e = blockIdx.x * blockDim.x + threadIdx.x; e < N_EDGES; e += gridDim.x * blockDim.x)
        atomicAdd(&cnt[dst[e]], 1);
}

__global__ void dinv_kernel(const int* __restrict__ cnt, float* __restrict__ dinv) {
    for (int i = blockIdx.x * blockDim.x + threadIdx.x; i < N_NODES; i += gridDim.x * blockDim.x)
        dinv[i] = rsqrtf((float)cnt[i] + 1.f);   // +1 self-loop
}

__global__ __launch_bounds__(1024) void scan_kernel(int* __restrict__ cnt, int* __restrict__ rowptr) {
    __shared__ int part[1024];
    const int CH = 49;
    int t = threadIdx.x;
    int base = t * CH;
    int s = 0;
    for (int i = 0; i < CH; ++i) {
        int idx = base + i;
        if (idx < N_NODES) s += cnt[idx];
    }
    part[t] = s;
    __syncthreads();
    for (int off = 1; off < 1024; off <<= 1) {
        int v = (t >= off) ? part[t - off] : 0;
        __syncthreads();
        part[t] += v;
        __syncthreads();
    }
    int run = (t == 0) ? 0 : part[t - 1];
    for (int i = 0; i < CH; ++i) {
        int idx = base + i;
        if (idx < N_NODES) {
            int c = cnt[idx];
            rowptr[idx] = run;
            run += c;
            cnt[idx] = 0;
        }
    }
    if (t == 1023) rowptr[N_NODES] = run;
}

__global__ void fill_kernel(const int* __restrict__ ei, const int* __restrict__ rowptr,
                            int* __restrict__ fill, const float* __restrict__ dinv,
                            int2* __restrict__ csr) {
    const int* src = ei;
    const int* dst = ei + N_EDGES;
    for (int e = blockIdx.x * blockDim.x + threadIdx.x; e < N_EDGES; e += gridDim.x * blockDim.x) {
        int s = src[e], d = dst[e];
        int pos = rowptr[d] + atomicAdd(&fill[d], 1);
        csr[pos] = make_int2(s, __float_as_int(dinv[s] * dinv[d]));
    }
}

__global__ void gcount_kernel(const int* __restrict__ batch, float* __restrict__ cntg) {
    for (int i = blockIdx.x * blockDim.x + threadIdx.x; i < N_NODES; i += gridDim.x * blockDim.x)
        atomicAdd(&cntg[batch[i]], 1.f);
}

// ---------------- GEMM: C[M,128] = A[M,K] @ B[K,128], fp32 math ----------------
// Output bf16, CHUNK-MAJOR: C[(col>>5)*N + r]*32 + (col&31)
template<int K>
__global__ __launch_bounds__(256) void gemm_n128(const float* __restrict__ A,
                                                 const float* __restrict__ B,
                                                 unsigned short* __restrict__ C, int M) {
    constexpr int BK = 16;
    __shared__ float As[BK][68];
    __shared__ float Bs[BK][132];

    const int tid = threadIdx.x;
    const int tx  = tid & 31;
    const int ty  = tid >> 5;
    const int row0 = blockIdx.x * 64;

    const int lar = tid >> 2;
    const int lak = (tid & 3) * 4;
    const int lbk = tid >> 4;
    const int lbc = (tid & 15) * 8;

    float acc[8][4];
    #pragma unroll
    for (int i = 0; i < 8; ++i)
        #pragma unroll
        for (int j = 0; j < 4; ++j) acc[i][j] = 0.f;

    int arow = row0 + lar;
    if (arow >= M) arow = M - 1;
    const float* Aptr = A + (long)arow * K + lak;
    const float* Bptr = B + (long)lbk * 128 + lbc;

    for (int k0 = 0; k0 < K; k0 += BK) {
        float4 av = *(const float4*)(Aptr + k0);
        As[lak + 0][lar] = av.x;
        As[lak + 1][lar] = av.y;
        As[lak + 2][lar] = av.z;
        As[lak + 3][lar] = av.w;
        float4 bv0 = *(const float4*)(Bptr + (long)k0 * 128);
        float4 bv1 = *(const float4*)(Bptr + (long)k0 * 128 + 4);
        *(float4*)&Bs[lbk][lbc]     = bv0;
        *(float4*)&Bs[lbk][lbc + 4] = bv1;
        __syncthreads();
        #pragma unroll
        for (int kk = 0; kk < BK; ++kk) {
            float4 b4 = *(const float4*)&Bs[kk][tx * 4];
            float4 a0 = *(const float4*)&As[kk][ty * 8];
            float4 a1 = *(const float4*)&As[kk][ty * 8 + 4];
            float a[8] = {a0.x, a0.y, a0.z, a0.w, a1.x, a1.y, a1.z, a1.w};
            float b[4] = {b4.x, b4.y, b4.z, b4.w};
            #pragma unroll
            for (int i = 0; i < 8; ++i)
                #pragma unroll
                for (int j = 0; j < 4; ++j)
                    acc[i][j] = fmaf(a[i], b[j], acc[i][j]);
        }
        __syncthreads();
    }

    const int col   = tx * 4;
    const int chunk = col >> 5;
    const int cin   = col & 31;
    #pragma unroll
    for (int i = 0; i < 8; ++i) {
        int r = row0 + ty * 8 + i;
        if (r < M) {
            ushort4 v;
            v.x = f2bf(acc[i][0]); v.y = f2bf(acc[i][1]);
            v.z = f2bf(acc[i][2]); v.w = f2bf(acc[i][3]);
            *(ushort4*)(C + ((long)chunk * N_NODES + r) * 32 + cin) = v;
        }
    }
}

// ---------------- chunked CSR gather: one 64B line per (node,chunk) ----------------
// Per pass (chunk): random working set = 3.2 MB -> per-XCD L2 resident.
// Lane layout: es = lane>>2 (16 edge slots), cl = lane&3 (8 channels each).
// MODE 0: outbuf[node*128 + chunk*32 + ...] = relu(agg + bias)  (fp32)
// MODE 1: z_partial = dot(relu(agg+bias), Wl_chunk); zsumR[rep][batch] += z
#define GATHER_BLOCKS 2048
template<int MODE>
__global__ __launch_bounds__(256, 8) void gather_chunk_kernel(
        const unsigned short* __restrict__ xlc, const float* __restrict__ dinv,
        const int* __restrict__ rowptr, const int2* __restrict__ csr,
        const float* __restrict__ bias, float* __restrict__ outbuf,
        const float* __restrict__ Wl, const int* __restrict__ batch,
        float* __restrict__ zsumR, int chunk) {
    const int lane = threadIdx.x & 63;
    const int es = lane >> 2;       // edge slot 0..15
    const int cl = lane & 3;        // channel lane
    const int c0 = cl * 8;          // channel offset within chunk
    const int gch = chunk * 32 + c0;

    const unsigned short* xc = xlc + (long)chunk * N_NODES * 32;

    const int wave   = blockIdx.x * 4 + (threadIdx.x >> 6);
    const int nwaves = GATHER_BLOCKS * 4;

    int node = wave;
    if (node >= N_NODES) return;
    int start = rowptr[node];
    int end   = rowptr[node + 1];

    for (; node < N_NODES; ) {
        int nxt = node + nwaves;
        int n_start = 0, n_end = 0;
        if (nxt < N_NODES) {
            n_start = rowptr[nxt];
            n_end   = rowptr[nxt + 1];
        }

        // self-loop line (issue early)
        u16x8 sv = *(const u16x8*)(xc + (long)node * 32 + c0);

        float acc[8];
        #pragma unroll
        for (int j = 0; j < 8; ++j) acc[j] = 0.f;

        for (int eb = start; eb < end; eb += 16) {
            int e  = eb + es;
            int ec = (e < end) ? e : start;
            int2 cw = csr[ec];
            float w = (e < end) ? __int_as_float(cw.y) : 0.f;
            u16x8 r = *(const u16x8*)(xc + (long)cw.x * 32 + c0);
            #pragma unroll
            for (int j = 0; j < 8; ++j)
                acc[j] = fmaf(w, bf2f(r[j]), acc[j]);
        }

        // reduce across the 16 edge slots (lane bits 2..5)
        #pragma unroll
        for (int j = 0; j < 8; ++j) {
            acc[j] += __shfl_xor(acc[j], 4);
            acc[j] += __shfl_xor(acc[j], 8);
            acc[j] += __shfl_xor(acc[j], 16);
            acc[j] += __shfl_xor(acc[j], 32);
        }

        // self-loop + bias + relu
        float di = dinv[node];
        float w2 = di * di;
        const float4 bb0 = *(const float4*)(bias + gch);
        const float4 bb1 = *(const float4*)(bias + gch + 4);
        float bv[8] = {bb0.x, bb0.y, bb0.z, bb0.w, bb1.x, bb1.y, bb1.z, bb1.w};
        float s[8];
        #pragma unroll
        for (int j = 0; j < 8; ++j)
            s[j] = fmaxf(fmaf(w2, bf2f(sv[j]), acc[j]) + bv[j], 0.f);

        if (MODE == 0) {
            if (es == 0) {   // lanes 0..3 cover the chunk's 32 channels
                float* op = outbuf + (long)node * 128 + gch;
                *(float4*)(op)     = make_float4(s[0], s[1], s[2], s[3]);
                *(float4*)(op + 4) = make_float4(s[4], s[5], s[6], s[7]);
            }
        } else {
            const float4 wl0 = *(const float4*)(Wl + gch);
            const float4 wl1 = *(const float4*)(Wl + gch + 4);
            float z = s[0]*wl0.x + s[1]*wl0.y + s[2]*wl0.z + s[3]*wl0.w
                    + s[4]*wl1.x + s[5]*wl1.y + s[6]*wl1.z + s[7]*wl1.w;
            z += __shfl_xor(z, 1);
            z += __shfl_xor(z, 2);
            if (lane == 0)
                atomicAdd(&zsumR[(blockIdx.x & (ZREP - 1)) * N_GRAPHS + batch[node]], z);
        }

        node = nxt;
        start = n_start;
        end = n_end;
    }
}

__global__ void out_kernel(const float* __restrict__ zsumR, const float* __restrict__ cntg,
                           const float* __restrict__ bl, float* __restrict__ out) {
    int g = threadIdx.x;
    if (g < N_GRAPHS) {
        float z = 0.f;
        #pragma unroll
        for (int r = 0; r < ZREP; ++r) z += zsumR[r * N_GRAPHS + g];
        out[g] = z / fmaxf(cntg[g], 1.f) + bl[0];
    }
}

// ---------------- launch ----------------

extern "C" void kernel_launch(void* const* d_in, const int* in_sizes, int n_in,
                              void* d_out, int out_size, void* d_ws, size_t ws_size,
                              hipStream_t stream) {
    const float* x    = (const float*)d_in[0];
    const int*   ei   = (const int*)d_in[1];
    const int*   batch= (const int*)d_in[2];
    const float* W1   = (const float*)d_in[3];
    const float* b1   = (const float*)d_in[4];
    const float* W2   = (const float*)d_in[5];
    const float* b2   = (const float*)d_in[6];
    const float* Wl   = (const float*)d_in[7];
    const float* bl   = (const float*)d_in[8];
    float* out = (float*)d_out;

    // workspace layout (4B words)
    float* ws      = (float*)d_ws;
    float* dinv    = ws;                          // 50176
    float* zsumR   = ws + 50176;                  // ZREP*64 = 1024
    float* cntg    = ws + 51200;                  // 64
    int*   cnt_i   = (int*)(ws + 51264);          // 50176 (also fill counters)
    int*   rowptr  = (int*)(ws + 101440);         // 50176 (50001 used)
    int2*  csr     = (int2*)(ws + 151616);        // 800000 int2 (word off even -> 8B ok)
    unsigned short* xl16 = (unsigned short*)(ws + 1751616);  // [4][N][32] bf16 = 6.4M u16
    float* h1      = ws + 1751616 + 3200000;      // 6.4M fp32 [node][128]

    // zero zsumR + cntg + cnt_i (contiguous)
    zero_int_kernel<<<128, 256, 0, stream>>>((int*)(ws + 50176), 1024 + 64 + 50176);

    hist_kernel<<<1024, 256, 0, stream>>>(ei, cnt_i);
    dinv_kernel<<<128, 256, 0, stream>>>(cnt_i, dinv);
    scan_kernel<<<1, 1024, 0, stream>>>(cnt_i, rowptr);
    fill_kernel<<<1024, 256, 0, stream>>>(ei, rowptr, cnt_i, dinv, csr);
    gcount_kernel<<<256, 256, 0, stream>>>(batch, cntg);

    // layer 1: xl1 = x@W1 (chunk-major bf16), then per-chunk gather -> h1 (fp32)
    gemm_n128<768><<<782, 256, 0, stream>>>(x, W1, xl16, N_NODES);
    for (int c = 0; c < N_CHUNK; ++c)
        gather_chunk_kernel<0><<<GATHER_BLOCKS, 256, 0, stream>>>(
            xl16, dinv, rowptr, csr, b1, h1, nullptr, nullptr, nullptr, c);

    // layer 2: xl2 = h1@W2 (chunk-major bf16), per-chunk gather + pool
    gemm_n128<128><<<782, 256, 0, stream>>>(h1, W2, xl16, N_NODES);
    for (int c = 0; c < N_CHUNK; ++c)
        gather_chunk_kernel<1><<<GATHER_BLOCKS, 256, 0, stream>>>(
            xl16, dinv, rowptr, csr, b2, nullptr, Wl, batch, zsumR, c);

    out_kernel<<<1, 64, 0, stream>>>(zsumR, cntg, bl, out);
}

// Round 8
// 647.012 us; speedup vs baseline: 1.7002x; 1.4516x over previous
//
#include <hip/hip_runtime.h>

#define N_NODES  50000
#define N_EDGES  800000
#define N_GRAPHS 64
#define N_CHUNK  4          // 128 channels / 32
#define ZREP     16         // zsum replicas

typedef unsigned short u16x8 __attribute__((ext_vector_type(8)));

__device__ __forceinline__ float bf2f(unsigned short h) {
    return __uint_as_float((unsigned)h << 16);
}
__device__ __forceinline__ unsigned short f2bf(float f) {
    unsigned u = __float_as_uint(f);
    unsigned r = (u + 0x7FFFu + ((u >> 16) & 1u)) >> 16;   // RNE
    return (unsigned short)r;
}

// ---------------- utility kernels ----------------

__global__ void zero_int_kernel(int* __restrict__ p, int n) {
    for (int i = blockIdx.x * blockDim.x + threadIdx.x; i < n; i += gridDim.x * blockDim.x)
        p[i] = 0;
}

__global__ void hist_kernel(const int* __restrict__ ei, int* __restrict__ cnt) {
    const int* dst = ei + N_EDGES;
    for (int e = blockIdx.x * blockDim.x + threadIdx.x; e < N_EDGES; e += gridDim.x * blockDim.x)
        atomicAdd(&cnt[dst[e]], 1);
}

__global__ void dinv_kernel(const int* __restrict__ cnt, float* __restrict__ dinv) {
    for (int i = blockIdx.x * blockDim.x + threadIdx.x; i < N_NODES; i += gridDim.x * blockDim.x)
        dinv[i] = rsqrtf((float)cnt[i] + 1.f);   // +1 self-loop
}

__global__ __launch_bounds__(1024) void scan_kernel(int* __restrict__ cnt, int* __restrict__ rowptr) {
    __shared__ int part[1024];
    const int CH = 49;
    int t = threadIdx.x;
    int base = t * CH;
    int s = 0;
    for (int i = 0; i < CH; ++i) {
        int idx = base + i;
        if (idx < N_NODES) s += cnt[idx];
    }
    part[t] = s;
    __syncthreads();
    for (int off = 1; off < 1024; off <<= 1) {
        int v = (t >= off) ? part[t - off] : 0;
        __syncthreads();
        part[t] += v;
        __syncthreads();
    }
    int run = (t == 0) ? 0 : part[t - 1];
    for (int i = 0; i < CH; ++i) {
        int idx = base + i;
        if (idx < N_NODES) {
            int c = cnt[idx];
            rowptr[idx] = run;
            run += c;
            cnt[idx] = 0;
        }
    }
    if (t == 1023) rowptr[N_NODES] = run;
}

__global__ void fill_kernel(const int* __restrict__ ei, const int* __restrict__ rowptr,
                            int* __restrict__ fill, const float* __restrict__ dinv,
                            int2* __restrict__ csr) {
    const int* src = ei;
    const int* dst = ei + N_EDGES;
    for (int e = blockIdx.x * blockDim.x + threadIdx.x; e < N_EDGES; e += gridDim.x * blockDim.x) {
        int s = src[e], d = dst[e];
        int pos = rowptr[d] + atomicAdd(&fill[d], 1);
        csr[pos] = make_int2(s, __float_as_int(dinv[s] * dinv[d]));
    }
}

// batch is SORTED: per-graph count via binary search, no atomics
__global__ void gcount_bs_kernel(const int* __restrict__ batch, float* __restrict__ cntg) {
    int g = threadIdx.x;
    if (g >= N_GRAPHS) return;
    int lo = 0, hi = N_NODES;                // lower_bound(g)
    while (lo < hi) { int mid = (lo + hi) >> 1; if (batch[mid] < g) lo = mid + 1; else hi = mid; }
    int a = lo;
    lo = 0; hi = N_NODES;                    // lower_bound(g+1)
    while (lo < hi) { int mid = (lo + hi) >> 1; if (batch[mid] < g + 1) lo = mid + 1; else hi = mid; }
    cntg[g] = (float)(lo - a);
}

// ---------------- GEMM: C[M,128] = A[M,K] @ B[K,128], fp32 math ----------------
// Output bf16, CHUNK-MAJOR: C[(col>>5)*N + r]*32 + (col&31)
template<int K>
__global__ __launch_bounds__(256) void gemm_n128(const float* __restrict__ A,
                                                 const float* __restrict__ B,
                                                 unsigned short* __restrict__ C, int M) {
    constexpr int BK = 16;
    __shared__ float As[BK][68];
    __shared__ float Bs[BK][132];

    const int tid = threadIdx.x;
    const int tx  = tid & 31;
    const int ty  = tid >> 5;
    const int row0 = blockIdx.x * 64;

    const int lar = tid >> 2;
    const int lak = (tid & 3) * 4;
    const int lbk = tid >> 4;
    const int lbc = (tid & 15) * 8;

    float acc[8][4];
    #pragma unroll
    for (int i = 0; i < 8; ++i)
        #pragma unroll
        for (int j = 0; j < 4; ++j) acc[i][j] = 0.f;

    int arow = row0 + lar;
    if (arow >= M) arow = M - 1;
    const float* Aptr = A + (long)arow * K + lak;
    const float* Bptr = B + (long)lbk * 128 + lbc;

    for (int k0 = 0; k0 < K; k0 += BK) {
        float4 av = *(const float4*)(Aptr + k0);
        As[lak + 0][lar] = av.x;
        As[lak + 1][lar] = av.y;
        As[lak + 2][lar] = av.z;
        As[lak + 3][lar] = av.w;
        float4 bv0 = *(const float4*)(Bptr + (long)k0 * 128);
        float4 bv1 = *(const float4*)(Bptr + (long)k0 * 128 + 4);
        *(float4*)&Bs[lbk][lbc]     = bv0;
        *(float4*)&Bs[lbk][lbc + 4] = bv1;
        __syncthreads();
        #pragma unroll
        for (int kk = 0; kk < BK; ++kk) {
            float4 b4 = *(const float4*)&Bs[kk][tx * 4];
            float4 a0 = *(const float4*)&As[kk][ty * 8];
            float4 a1 = *(const float4*)&As[kk][ty * 8 + 4];
            float a[8] = {a0.x, a0.y, a0.z, a0.w, a1.x, a1.y, a1.z, a1.w};
            float b[4] = {b4.x, b4.y, b4.z, b4.w};
            #pragma unroll
            for (int i = 0; i < 8; ++i)
                #pragma unroll
                for (int j = 0; j < 4; ++j)
                    acc[i][j] = fmaf(a[i], b[j], acc[i][j]);
        }
        __syncthreads();
    }

    const int col   = tx * 4;
    const int chunk = col >> 5;
    const int cin   = col & 31;
    #pragma unroll
    for (int i = 0; i < 8; ++i) {
        int r = row0 + ty * 8 + i;
        if (r < M) {
            ushort4 v;
            v.x = f2bf(acc[i][0]); v.y = f2bf(acc[i][1]);
            v.z = f2bf(acc[i][2]); v.w = f2bf(acc[i][3]);
            *(ushort4*)(C + ((long)chunk * N_NODES + r) * 32 + cin) = v;
        }
    }
}

// ---------------- chunked CSR gather: one 64B line per (node,chunk) ----------------
// Per pass (chunk): random working set = 3.2 MB -> per-XCD L2 resident.
// Lane layout: es = lane>>2 (16 edge slots), cl = lane&3 (8 channels each).
// MODE 0: outbuf[node*128 + chunk*32 + ...] = relu(agg + bias)  (fp32)
// MODE 1: z_partial = dot(relu(agg+bias), Wl_chunk); zsumR[rep][batch] += z
#define GATHER_BLOCKS 2048
template<int MODE>
__global__ __launch_bounds__(256, 8) void gather_chunk_kernel(
        const unsigned short* __restrict__ xlc, const float* __restrict__ dinv,
        const int* __restrict__ rowptr, const int2* __restrict__ csr,
        const float* __restrict__ bias, float* __restrict__ outbuf,
        const float* __restrict__ Wl, const int* __restrict__ batch,
        float* __restrict__ zsumR, int chunk) {
    const int lane = threadIdx.x & 63;
    const int es = lane >> 2;       // edge slot 0..15
    const int cl = lane & 3;        // channel lane
    const int c0 = cl * 8;          // channel offset within chunk
    const int gch = chunk * 32 + c0;

    const unsigned short* xc = xlc + (long)chunk * N_NODES * 32;

    const int wave   = blockIdx.x * 4 + (threadIdx.x >> 6);
    const int nwaves = GATHER_BLOCKS * 4;

    int node = wave;
    if (node >= N_NODES) return;
    int start = rowptr[node];
    int end   = rowptr[node + 1];

    for (; node < N_NODES; ) {
        int nxt = node + nwaves;
        int n_start = 0, n_end = 0;
        if (nxt < N_NODES) {
            n_start = rowptr[nxt];
            n_end   = rowptr[nxt + 1];
        }

        // self-loop line (issue early)
        u16x8 sv = *(const u16x8*)(xc + (long)node * 32 + c0);

        float acc[8];
        #pragma unroll
        for (int j = 0; j < 8; ++j) acc[j] = 0.f;

        for (int eb = start; eb < end; eb += 16) {
            int e  = eb + es;
            int ec = (e < end) ? e : start;
            int2 cw = csr[ec];
            float w = (e < end) ? __int_as_float(cw.y) : 0.f;
            u16x8 r = *(const u16x8*)(xc + (long)cw.x * 32 + c0);
            #pragma unroll
            for (int j = 0; j < 8; ++j)
                acc[j] = fmaf(w, bf2f(r[j]), acc[j]);
        }

        // reduce across the 16 edge slots (lane bits 2..5)
        #pragma unroll
        for (int j = 0; j < 8; ++j) {
            acc[j] += __shfl_xor(acc[j], 4);
            acc[j] += __shfl_xor(acc[j], 8);
            acc[j] += __shfl_xor(acc[j], 16);
            acc[j] += __shfl_xor(acc[j], 32);
        }

        // self-loop + bias + relu
        float di = dinv[node];
        float w2 = di * di;
        const float4 bb0 = *(const float4*)(bias + gch);
        const float4 bb1 = *(const float4*)(bias + gch + 4);
        float bv[8] = {bb0.x, bb0.y, bb0.z, bb0.w, bb1.x, bb1.y, bb1.z, bb1.w};
        float s[8];
        #pragma unroll
        for (int j = 0; j < 8; ++j)
            s[j] = fmaxf(fmaf(w2, bf2f(sv[j]), acc[j]) + bv[j], 0.f);

        if (MODE == 0) {
            if (es == 0) {   // lanes 0..3 cover the chunk's 32 channels
                float* op = outbuf + (long)node * 128 + gch;
                *(float4*)(op)     = make_float4(s[0], s[1], s[2], s[3]);
                *(float4*)(op + 4) = make_float4(s[4], s[5], s[6], s[7]);
            }
        } else {
            const float4 wl0 = *(const float4*)(Wl + gch);
            const float4 wl1 = *(const float4*)(Wl + gch + 4);
            float z = s[0]*wl0.x + s[1]*wl0.y + s[2]*wl0.z + s[3]*wl0.w
                    + s[4]*wl1.x + s[5]*wl1.y + s[6]*wl1.z + s[7]*wl1.w;
            z += __shfl_xor(z, 1);
            z += __shfl_xor(z, 2);
            if (lane == 0)
                atomicAdd(&zsumR[(blockIdx.x & (ZREP - 1)) * N_GRAPHS + batch[node]], z);
        }

        node = nxt;
        start = n_start;
        end = n_end;
    }
}

__global__ void out_kernel(const float* __restrict__ zsumR, const float* __restrict__ cntg,
                           const float* __restrict__ bl, float* __restrict__ out) {
    int g = threadIdx.x;
    if (g < N_GRAPHS) {
        float z = 0.f;
        #pragma unroll
        for (int r = 0; r < ZREP; ++r) z += zsumR[r * N_GRAPHS + g];
        out[g] = z / fmaxf(cntg[g], 1.f) + bl[0];
    }
}

// ---------------- launch ----------------

extern "C" void kernel_launch(void* const* d_in, const int* in_sizes, int n_in,
                              void* d_out, int out_size, void* d_ws, size_t ws_size,
                              hipStream_t stream) {
    const float* x    = (const float*)d_in[0];
    const int*   ei   = (const int*)d_in[1];
    const int*   batch= (const int*)d_in[2];
    const float* W1   = (const float*)d_in[3];
    const float* b1   = (const float*)d_in[4];
    const float* W2   = (const float*)d_in[5];
    const float* b2   = (const float*)d_in[6];
    const float* Wl   = (const float*)d_in[7];
    const float* bl   = (const float*)d_in[8];
    float* out = (float*)d_out;

    // workspace layout (4B words)
    float* ws      = (float*)d_ws;
    float* dinv    = ws;                          // 50176
    float* zsumR   = ws + 50176;                  // ZREP*64 = 1024
    float* cntg    = ws + 51200;                  // 64
    int*   cnt_i   = (int*)(ws + 51264);          // 50176 (also fill counters)
    int*   rowptr  = (int*)(ws + 101440);         // 50176 (50001 used)
    int2*  csr     = (int2*)(ws + 151616);        // 800000 int2
    unsigned short* xl16 = (unsigned short*)(ws + 1751616);  // [4][N][32] bf16 = 6.4M u16
    float* h1      = ws + 1751616 + 3200000;      // 6.4M fp32 [node][128]

    // zero zsumR + cntg + cnt_i (contiguous)
    zero_int_kernel<<<128, 256, 0, stream>>>((int*)(ws + 50176), 1024 + 64 + 50176);

    hist_kernel<<<1024, 256, 0, stream>>>(ei, cnt_i);
    dinv_kernel<<<128, 256, 0, stream>>>(cnt_i, dinv);
    scan_kernel<<<1, 1024, 0, stream>>>(cnt_i, rowptr);
    fill_kernel<<<1024, 256, 0, stream>>>(ei, rowptr, cnt_i, dinv, csr);
    gcount_bs_kernel<<<1, 64, 0, stream>>>(batch, cntg);

    // layer 1: xl1 = x@W1 (chunk-major bf16), then per-chunk gather -> h1 (fp32)
    gemm_n128<768><<<782, 256, 0, stream>>>(x, W1, xl16, N_NODES);
    for (int c = 0; c < N_CHUNK; ++c)
        gather_chunk_kernel<0><<<GATHER_BLOCKS, 256, 0, stream>>>(
            xl16, dinv, rowptr, csr, b1, h1, nullptr, nullptr, nullptr, c);

    // layer 2: xl2 = h1@W2 (chunk-major bf16), per-chunk gather + pool
    gemm_n128<128><<<782, 256, 0, stream>>>(h1, W2, xl16, N_NODES);
    for (int c = 0; c < N_CHUNK; ++c)
        gather_chunk_kernel<1><<<GATHER_BLOCKS, 256, 0, stream>>>(
            xl16, dinv, rowptr, csr, b2, nullptr, Wl, batch, zsumR, c);

    out_kernel<<<1, 64, 0, stream>>>(zsumR, cntg, bl, out);
}

// Round 9
// 520.025 us; speedup vs baseline: 2.1154x; 1.2442x over previous
//
#include <hip/hip_runtime.h>

#define N_NODES  50000
#define N_EDGES  800000
#define N_GRAPHS 64
#define N_CHUNK  4          // 128 channels / 32
#define ZREP     16         // zsum replicas

typedef unsigned short u16x8 __attribute__((ext_vector_type(8)));
typedef short s16x8 __attribute__((ext_vector_type(8)));
typedef float f32x4 __attribute__((ext_vector_type(4)));

__device__ __forceinline__ float bf2f(unsigned short h) {
    return __uint_as_float((unsigned)h << 16);
}
__device__ __forceinline__ unsigned short f2bf(float f) {
    unsigned u = __float_as_uint(f);
    unsigned r = (u + 0x7FFFu + ((u >> 16) & 1u)) >> 16;   // RNE
    return (unsigned short)r;
}
__device__ __forceinline__ unsigned pk2(float a, float b) {
    return (unsigned)f2bf(a) | ((unsigned)f2bf(b) << 16);
}

// ---------------- utility kernels ----------------

__global__ void zero_int_kernel(int* __restrict__ p, int n) {
    for (int i = blockIdx.x * blockDim.x + threadIdx.x; i < n; i += gridDim.x * blockDim.x)
        p[i] = 0;
}

__global__ void hist_kernel(const int* __restrict__ ei, int* __restrict__ cnt) {
    const int* dst = ei + N_EDGES;
    for (int e = blockIdx.x * blockDim.x + threadIdx.x; e < N_EDGES; e += gridDim.x * blockDim.x)
        atomicAdd(&cnt[dst[e]], 1);
}

__global__ void dinv_kernel(const int* __restrict__ cnt, float* __restrict__ dinv) {
    for (int i = blockIdx.x * blockDim.x + threadIdx.x; i < N_NODES; i += gridDim.x * blockDim.x)
        dinv[i] = rsqrtf((float)cnt[i] + 1.f);   // +1 self-loop
}

__global__ __launch_bounds__(1024) void scan_kernel(int* __restrict__ cnt, int* __restrict__ rowptr) {
    __shared__ int part[1024];
    const int CH = 49;
    int t = threadIdx.x;
    int base = t * CH;
    int s = 0;
    for (int i = 0; i < CH; ++i) {
        int idx = base + i;
        if (idx < N_NODES) s += cnt[idx];
    }
    part[t] = s;
    __syncthreads();
    for (int off = 1; off < 1024; off <<= 1) {
        int v = (t >= off) ? part[t - off] : 0;
        __syncthreads();
        part[t] += v;
        __syncthreads();
    }
    int run = (t == 0) ? 0 : part[t - 1];
    for (int i = 0; i < CH; ++i) {
        int idx = base + i;
        if (idx < N_NODES) {
            int c = cnt[idx];
            rowptr[idx] = run;
            run += c;
            cnt[idx] = 0;
        }
    }
    if (t == 1023) rowptr[N_NODES] = run;
}

__global__ void fill_kernel(const int* __restrict__ ei, const int* __restrict__ rowptr,
                            int* __restrict__ fill, const float* __restrict__ dinv,
                            int2* __restrict__ csr) {
    const int* src = ei;
    const int* dst = ei + N_EDGES;
    for (int e = blockIdx.x * blockDim.x + threadIdx.x; e < N_EDGES; e += gridDim.x * blockDim.x) {
        int s = src[e], d = dst[e];
        int pos = rowptr[d] + atomicAdd(&fill[d], 1);
        csr[pos] = make_int2(s, __float_as_int(dinv[s] * dinv[d]));
    }
}

// batch is SORTED: per-graph count via binary search, no atomics
__global__ void gcount_bs_kernel(const int* __restrict__ batch, float* __restrict__ cntg) {
    int g = threadIdx.x;
    if (g >= N_GRAPHS) return;
    int lo = 0, hi = N_NODES;
    while (lo < hi) { int mid = (lo + hi) >> 1; if (batch[mid] < g) lo = mid + 1; else hi = mid; }
    int a = lo;
    lo = 0; hi = N_NODES;
    while (lo < hi) { int mid = (lo + hi) >> 1; if (batch[mid] < g + 1) lo = mid + 1; else hi = mid; }
    cntg[g] = (float)(lo - a);
}

// split W into hi/lo bf16, TRANSPOSED to [col][K]
__global__ void prep_w_kernel(const float* __restrict__ W1, const float* __restrict__ W2,
                              unsigned short* __restrict__ w1h, unsigned short* __restrict__ w1l,
                              unsigned short* __restrict__ w2h, unsigned short* __restrict__ w2l) {
    const int n1 = 768 * 128, n2 = 128 * 128;
    for (int i = blockIdx.x * blockDim.x + threadIdx.x; i < n1 + n2; i += gridDim.x * blockDim.x) {
        if (i < n1) {
            int k = i >> 7, c = i & 127;
            float w = W1[i];
            unsigned short hi = f2bf(w);
            unsigned short lo = f2bf(w - bf2f(hi));
            w1h[c * 768 + k] = hi;
            w1l[c * 768 + k] = lo;
        } else {
            int j = i - n1;
            int k = j >> 7, c = j & 127;
            float w = W2[j];
            unsigned short hi = f2bf(w);
            unsigned short lo = f2bf(w - bf2f(hi));
            w2h[c * 128 + k] = hi;
            w2l[c * 128 + k] = lo;
        }
    }
}

// ---------------- MFMA GEMM: C[M,128] = A[M,K] @ W[K,128] ----------------
// A fp32 (rounded to bf16 in staging), W pre-split hi/lo bf16 [col][K].
// Two chained mfma per fragment: acc += Whi*x + Wlo*x  => ~fp32-accurate W.
// Swapped operands (A-op = W^T, B-op = x) so each lane stores 4 consecutive
// cols at one row -> ushort4 chunk-major store: C[(c>>5)*N + r]*32 + (c&31).
// Tile 128x128, BK=32, 4 waves; wave w owns cols [w*32, w*32+32).
// LDS rows padded to 40 u16 (80 B): 16-lane frag reads are 2-way (free).
template<int K>
__global__ __launch_bounds__(256) void gemm_mfma(const float* __restrict__ A,
                                                 const unsigned short* __restrict__ Wth,
                                                 const unsigned short* __restrict__ Wtl,
                                                 unsigned short* __restrict__ C, int M) {
    __shared__ unsigned short Xs[128 * 40];
    __shared__ unsigned short Wh[128 * 40];
    __shared__ unsigned short Wl[128 * 40];

    const int tid  = threadIdx.x;
    const int row0 = blockIdx.x * 128;
    const int trow  = tid >> 1;          // 0..127 (X row / W col staged by this thread)
    const int thalf = (tid & 1) * 16;    // element offset 0 or 16

    int grow = row0 + trow;
    if (grow >= M) grow = M - 1;
    const float* xp = A + (long)grow * K + thalf;
    const unsigned short* wph = Wth + (long)trow * K + thalf;
    const unsigned short* wpl = Wtl + (long)trow * K + thalf;

    f32x4 acc[8][2];
    #pragma unroll
    for (int rf = 0; rf < 8; ++rf)
        #pragma unroll
        for (int cf = 0; cf < 2; ++cf)
            acc[rf][cf] = (f32x4){0.f, 0.f, 0.f, 0.f};

    // prefetch first X line (one aligned 64B line per thread)
    float4 f0 = *(const float4*)(xp);
    float4 f1 = *(const float4*)(xp + 4);
    float4 f2 = *(const float4*)(xp + 8);
    float4 f3 = *(const float4*)(xp + 12);

    const int l   = tid & 63;
    const int wv  = tid >> 6;
    const int lr  = l & 15;
    const int lk8 = (l >> 4) * 8;

    for (int k0 = 0; k0 < K; k0 += 32) {
        // stage W (L2-hot across blocks)
        uint4 wh0 = ((const uint4*)(wph + k0))[0];
        uint4 wh1 = ((const uint4*)(wph + k0))[1];
        uint4 wl0 = ((const uint4*)(wpl + k0))[0];
        uint4 wl1 = ((const uint4*)(wpl + k0))[1];
        unsigned short* xrow = &Xs[trow * 40 + thalf];
        *(uint4*)(xrow)     = make_uint4(pk2(f0.x, f0.y), pk2(f0.z, f0.w), pk2(f1.x, f1.y), pk2(f1.z, f1.w));
        *(uint4*)(xrow + 8) = make_uint4(pk2(f2.x, f2.y), pk2(f2.z, f2.w), pk2(f3.x, f3.y), pk2(f3.z, f3.w));
        *(uint4*)&Wh[trow * 40 + thalf]     = wh0;
        *(uint4*)&Wh[trow * 40 + thalf + 8] = wh1;
        *(uint4*)&Wl[trow * 40 + thalf]     = wl0;
        *(uint4*)&Wl[trow * 40 + thalf + 8] = wl1;
        __syncthreads();

        // prefetch next X line (hides HBM latency under MFMA)
        if (k0 + 32 < K) {
            f0 = *(const float4*)(xp + k0 + 32);
            f1 = *(const float4*)(xp + k0 + 36);
            f2 = *(const float4*)(xp + k0 + 40);
            f3 = *(const float4*)(xp + k0 + 44);
        }

        // fragments
        s16x8 xb[8], whf[2], wlf[2];
        #pragma unroll
        for (int rf = 0; rf < 8; ++rf)
            xb[rf] = *(const s16x8*)&Xs[(rf * 16 + lr) * 40 + lk8];
        #pragma unroll
        for (int cf = 0; cf < 2; ++cf) {
            whf[cf] = *(const s16x8*)&Wh[(wv * 32 + cf * 16 + lr) * 40 + lk8];
            wlf[cf] = *(const s16x8*)&Wl[(wv * 32 + cf * 16 + lr) * 40 + lk8];
        }
        #pragma unroll
        for (int rf = 0; rf < 8; ++rf)
            #pragma unroll
            for (int cf = 0; cf < 2; ++cf) {
                acc[rf][cf] = __builtin_amdgcn_mfma_f32_16x16x32_bf16(wlf[cf], xb[rf], acc[rf][cf], 0, 0, 0);
                acc[rf][cf] = __builtin_amdgcn_mfma_f32_16x16x32_bf16(whf[cf], xb[rf], acc[rf][cf], 0, 0, 0);
            }
        __syncthreads();
    }

    // store: lane -> row r = row0 + rf*16 + lr, 4 consecutive cols
    const int c4 = (l >> 4) * 4;
    #pragma unroll
    for (int rf = 0; rf < 8; ++rf) {
        int r = row0 + rf * 16 + lr;
        if (r < M) {
            #pragma unroll
            for (int cf = 0; cf < 2; ++cf) {
                int cb = wv * 32 + cf * 16 + c4;
                ushort4 v;
                v.x = f2bf(acc[rf][cf][0]);
                v.y = f2bf(acc[rf][cf][1]);
                v.z = f2bf(acc[rf][cf][2]);
                v.w = f2bf(acc[rf][cf][3]);
                *(ushort4*)(C + ((long)(cb >> 5) * N_NODES + r) * 32 + (cb & 31)) = v;
            }
        }
    }
}

// ---------------- chunked CSR gather: one 64B line per (node,chunk) ----------------
#define GATHER_BLOCKS 2048
template<int MODE>
__global__ __launch_bounds__(256, 8) void gather_chunk_kernel(
        const unsigned short* __restrict__ xlc, const float* __restrict__ dinv,
        const int* __restrict__ rowptr, const int2* __restrict__ csr,
        const float* __restrict__ bias, float* __restrict__ outbuf,
        const float* __restrict__ Wl, const int* __restrict__ batch,
        float* __restrict__ zsumR, int chunk) {
    const int lane = threadIdx.x & 63;
    const int es = lane >> 2;       // edge slot 0..15
    const int cl = lane & 3;        // channel lane
    const int c0 = cl * 8;          // channel offset within chunk
    const int gch = chunk * 32 + c0;

    const unsigned short* xc = xlc + (long)chunk * N_NODES * 32;

    const int wave   = blockIdx.x * 4 + (threadIdx.x >> 6);
    const int nwaves = GATHER_BLOCKS * 4;

    int node = wave;
    if (node >= N_NODES) return;
    int start = rowptr[node];
    int end   = rowptr[node + 1];

    for (; node < N_NODES; ) {
        int nxt = node + nwaves;
        int n_start = 0, n_end = 0;
        if (nxt < N_NODES) {
            n_start = rowptr[nxt];
            n_end   = rowptr[nxt + 1];
        }

        u16x8 sv = *(const u16x8*)(xc + (long)node * 32 + c0);

        float acc[8];
        #pragma unroll
        for (int j = 0; j < 8; ++j) acc[j] = 0.f;

        for (int eb = start; eb < end; eb += 16) {
            int e  = eb + es;
            int ec = (e < end) ? e : start;
            int2 cw = csr[ec];
            float w = (e < end) ? __int_as_float(cw.y) : 0.f;
            u16x8 r = *(const u16x8*)(xc + (long)cw.x * 32 + c0);
            #pragma unroll
            for (int j = 0; j < 8; ++j)
                acc[j] = fmaf(w, bf2f(r[j]), acc[j]);
        }

        #pragma unroll
        for (int j = 0; j < 8; ++j) {
            acc[j] += __shfl_xor(acc[j], 4);
            acc[j] += __shfl_xor(acc[j], 8);
            acc[j] += __shfl_xor(acc[j], 16);
            acc[j] += __shfl_xor(acc[j], 32);
        }

        float di = dinv[node];
        float w2 = di * di;
        const float4 bb0 = *(const float4*)(bias + gch);
        const float4 bb1 = *(const float4*)(bias + gch + 4);
        float bv[8] = {bb0.x, bb0.y, bb0.z, bb0.w, bb1.x, bb1.y, bb1.z, bb1.w};
        float s[8];
        #pragma unroll
        for (int j = 0; j < 8; ++j)
            s[j] = fmaxf(fmaf(w2, bf2f(sv[j]), acc[j]) + bv[j], 0.f);

        if (MODE == 0) {
            if (es == 0) {
                float* op = outbuf + (long)node * 128 + gch;
                *(float4*)(op)     = make_float4(s[0], s[1], s[2], s[3]);
                *(float4*)(op + 4) = make_float4(s[4], s[5], s[6], s[7]);
            }
        } else {
            const float4 wl0 = *(const float4*)(Wl + gch);
            const float4 wl1 = *(const float4*)(Wl + gch + 4);
            float z = s[0]*wl0.x + s[1]*wl0.y + s[2]*wl0.z + s[3]*wl0.w
                    + s[4]*wl1.x + s[5]*wl1.y + s[6]*wl1.z + s[7]*wl1.w;
            z += __shfl_xor(z, 1);
            z += __shfl_xor(z, 2);
            if (lane == 0)
                atomicAdd(&zsumR[(blockIdx.x & (ZREP - 1)) * N_GRAPHS + batch[node]], z);
        }

        node = nxt;
        start = n_start;
        end = n_end;
    }
}

__global__ void out_kernel(const float* __restrict__ zsumR, const float* __restrict__ cntg,
                           const float* __restrict__ bl, float* __restrict__ out) {
    int g = threadIdx.x;
    if (g < N_GRAPHS) {
        float z = 0.f;
        #pragma unroll
        for (int r = 0; r < ZREP; ++r) z += zsumR[r * N_GRAPHS + g];
        out[g] = z / fmaxf(cntg[g], 1.f) + bl[0];
    }
}

// ---------------- launch ----------------

extern "C" void kernel_launch(void* const* d_in, const int* in_sizes, int n_in,
                              void* d_out, int out_size, void* d_ws, size_t ws_size,
                              hipStream_t stream) {
    const float* x    = (const float*)d_in[0];
    const int*   ei   = (const int*)d_in[1];
    const int*   batch= (const int*)d_in[2];
    const float* W1   = (const float*)d_in[3];
    const float* b1   = (const float*)d_in[4];
    const float* W2   = (const float*)d_in[5];
    const float* b2   = (const float*)d_in[6];
    const float* Wl   = (const float*)d_in[7];
    const float* bl   = (const float*)d_in[8];
    float* out = (float*)d_out;

    // workspace layout (4B words)
    float* ws      = (float*)d_ws;
    float* dinv    = ws;                          // 50176
    float* zsumR   = ws + 50176;                  // 1024
    float* cntg    = ws + 51200;                  // 64
    int*   cnt_i   = (int*)(ws + 51264);          // 50176
    int*   rowptr  = (int*)(ws + 101440);         // 50176
    int2*  csr     = (int2*)(ws + 151616);        // 800000 int2
    unsigned short* xl16 = (unsigned short*)(ws + 1751616);  // [4][N][32] bf16
    float* h1      = ws + 1751616 + 3200000;      // 6.4M fp32 [node][128]
    unsigned short* w1h = (unsigned short*)(ws + 11351616);  // 98304 u16
    unsigned short* w1l = w1h + 98304;
    unsigned short* w2h = w1l + 98304;            // 16384 u16
    unsigned short* w2l = w2h + 16384;

    zero_int_kernel<<<128, 256, 0, stream>>>((int*)(ws + 50176), 1024 + 64 + 50176);

    hist_kernel<<<1024, 256, 0, stream>>>(ei, cnt_i);
    dinv_kernel<<<128, 256, 0, stream>>>(cnt_i, dinv);
    scan_kernel<<<1, 1024, 0, stream>>>(cnt_i, rowptr);
    fill_kernel<<<1024, 256, 0, stream>>>(ei, rowptr, cnt_i, dinv, csr);
    gcount_bs_kernel<<<1, 64, 0, stream>>>(batch, cntg);
    prep_w_kernel<<<448, 256, 0, stream>>>(W1, W2, w1h, w1l, w2h, w2l);

    // layer 1: xl1 = x@W1 (chunk-major bf16 via MFMA), per-chunk gather -> h1
    gemm_mfma<768><<<391, 256, 0, stream>>>(x, w1h, w1l, xl16, N_NODES);
    for (int c = 0; c < N_CHUNK; ++c)
        gather_chunk_kernel<0><<<GATHER_BLOCKS, 256, 0, stream>>>(
            xl16, dinv, rowptr, csr, b1, h1, nullptr, nullptr, nullptr, c);

    // layer 2: xl2 = h1@W2, per-chunk gather + pool
    gemm_mfma<128><<<391, 256, 0, stream>>>(h1, w2h, w2l, xl16, N_NODES);
    for (int c = 0; c < N_CHUNK; ++c)
        gather_chunk_kernel<1><<<GATHER_BLOCKS, 256, 0, stream>>>(
            xl16, dinv, rowptr, csr, b2, nullptr, Wl, batch, zsumR, c);

    out_kernel<<<1, 64, 0, stream>>>(zsumR, cntg, bl, out);
}

// Round 10
// 401.972 us; speedup vs baseline: 2.7367x; 1.2937x over previous
//
#include <hip/hip_runtime.h>

#define N_NODES  50000
#define N_EDGES  800000
#define N_GRAPHS 64
#define N_CHUNK  4          // 128 channels / 32
#define ZREP     16         // zsum replicas
#define SCAN_BLOCKS 196     // 196*256 = 50176

typedef unsigned short u16x8 __attribute__((ext_vector_type(8)));
typedef short s16x8 __attribute__((ext_vector_type(8)));
typedef float f32x4 __attribute__((ext_vector_type(4)));

__device__ __forceinline__ float bf2f(unsigned short h) {
    return __uint_as_float((unsigned)h << 16);
}
__device__ __forceinline__ unsigned short f2bf(float f) {
    unsigned u = __float_as_uint(f);
    unsigned r = (u + 0x7FFFu + ((u >> 16) & 1u)) >> 16;   // RNE
    return (unsigned short)r;
}
__device__ __forceinline__ unsigned pk2(float a, float b) {
    return (unsigned)f2bf(a) | ((unsigned)f2bf(b) << 16);
}

// ---------------- utility kernels ----------------

__global__ void zero_int_kernel(int* __restrict__ p, int n) {
    for (int i = blockIdx.x * blockDim.x + threadIdx.x; i < n; i += gridDim.x * blockDim.x)
        p[i] = 0;
}

__global__ void hist_kernel(const int* __restrict__ ei, int* __restrict__ cnt) {
    const int* dst = ei + N_EDGES;
    for (int e = blockIdx.x * blockDim.x + threadIdx.x; e < N_EDGES; e += gridDim.x * blockDim.x)
        atomicAdd(&cnt[dst[e]], 1);
}

__global__ void dinv_kernel(const int* __restrict__ cnt, float* __restrict__ dinv) {
    for (int i = blockIdx.x * blockDim.x + threadIdx.x; i < N_NODES; i += gridDim.x * blockDim.x)
        dinv[i] = rsqrtf((float)cnt[i] + 1.f);   // +1 self-loop
}

// ---- 3-phase multi-block exclusive scan of cnt[50176] -> rowptr ----
__global__ void scanA_kernel(const int* __restrict__ cnt, int* __restrict__ bsum) {
    __shared__ int wsum[4];
    int t = threadIdx.x;
    int v = cnt[blockIdx.x * 256 + t];
    #pragma unroll
    for (int off = 1; off < 64; off <<= 1) v += __shfl_xor(v, off);
    if ((t & 63) == 0) wsum[t >> 6] = v;
    __syncthreads();
    if (t == 0) bsum[blockIdx.x] = wsum[0] + wsum[1] + wsum[2] + wsum[3];
}

__global__ void scanB_kernel(const int* __restrict__ bsum, int* __restrict__ boff) {
    __shared__ int wsum[4];
    int t = threadIdx.x;
    int lane = t & 63, w = t >> 6;
    int v = (t < SCAN_BLOCKS) ? bsum[t] : 0;
    int s = v;
    #pragma unroll
    for (int off = 1; off < 64; off <<= 1) {
        int u = __shfl_up(s, off);
        if (lane >= off) s += u;
    }
    if (lane == 63) wsum[w] = s;
    __syncthreads();
    int wo = 0;
    for (int j = 0; j < w; ++j) wo += wsum[j];
    if (t < SCAN_BLOCKS) boff[t] = wo + s - v;   // exclusive
}

__global__ void scanC_kernel(int* __restrict__ cnt, const int* __restrict__ boff,
                             int* __restrict__ rowptr) {
    __shared__ int wsum[4];
    int t = threadIdx.x;
    int i = blockIdx.x * 256 + t;
    int lane = t & 63, w = t >> 6;
    int v = cnt[i];
    int s = v;
    #pragma unroll
    for (int off = 1; off < 64; off <<= 1) {
        int u = __shfl_up(s, off);
        if (lane >= off) s += u;
    }
    if (lane == 63) wsum[w] = s;
    __syncthreads();
    int wo = 0;
    for (int j = 0; j < w; ++j) wo += wsum[j];
    rowptr[i] = boff[blockIdx.x] + wo + s - v;   // i==N_NODES slot gets total E
    cnt[i] = 0;                                  // reset for fill pass
}

__global__ void fill_kernel(const int* __restrict__ ei, const int* __restrict__ rowptr,
                            int* __restrict__ fill, const float* __restrict__ dinv,
                            int2* __restrict__ csr) {
    const int* src = ei;
    const int* dst = ei + N_EDGES;
    for (int e = blockIdx.x * blockDim.x + threadIdx.x; e < N_EDGES; e += gridDim.x * blockDim.x) {
        int s = src[e], d = dst[e];
        int pos = rowptr[d] + atomicAdd(&fill[d], 1);
        csr[pos] = make_int2(s, __float_as_int(dinv[s] * dinv[d]));
    }
}

// batch is SORTED: per-graph count via binary search, no atomics
__global__ void gcount_bs_kernel(const int* __restrict__ batch, float* __restrict__ cntg) {
    int g = threadIdx.x;
    if (g >= N_GRAPHS) return;
    int lo = 0, hi = N_NODES;
    while (lo < hi) { int mid = (lo + hi) >> 1; if (batch[mid] < g) lo = mid + 1; else hi = mid; }
    int a = lo;
    lo = 0; hi = N_NODES;
    while (lo < hi) { int mid = (lo + hi) >> 1; if (batch[mid] < g + 1) lo = mid + 1; else hi = mid; }
    cntg[g] = (float)(lo - a);
}

// split W into hi/lo bf16, TRANSPOSED to [col][K]
__global__ void prep_w_kernel(const float* __restrict__ W1, const float* __restrict__ W2,
                              unsigned short* __restrict__ w1h, unsigned short* __restrict__ w1l,
                              unsigned short* __restrict__ w2h, unsigned short* __restrict__ w2l) {
    const int n1 = 768 * 128, n2 = 128 * 128;
    for (int i = blockIdx.x * blockDim.x + threadIdx.x; i < n1 + n2; i += gridDim.x * blockDim.x) {
        if (i < n1) {
            int k = i >> 7, c = i & 127;
            float w = W1[i];
            unsigned short hi = f2bf(w);
            unsigned short lo = f2bf(w - bf2f(hi));
            w1h[c * 768 + k] = hi;
            w1l[c * 768 + k] = lo;
        } else {
            int j = i - n1;
            int k = j >> 7, c = j & 127;
            float w = W2[j];
            unsigned short hi = f2bf(w);
            unsigned short lo = f2bf(w - bf2f(hi));
            w2h[c * 128 + k] = hi;
            w2l[c * 128 + k] = lo;
        }
    }
}

// ---------------- MFMA GEMM: C[M,128] = A[M,K] @ W[K,128] ----------------
// A fp32 (rounded to bf16 in staging), W pre-split hi/lo bf16 [col][K].
// Two chained mfma per fragment: acc += Whi*x + Wlo*x  => ~fp32-accurate W.
// Swapped operands (A-op = W^T, B-op = x); chunk-major ushort4 stores.
// Tile 128x128, BK=32, 4 waves; LDS rows padded to 40 u16.
template<int K>
__global__ __launch_bounds__(256) void gemm_mfma(const float* __restrict__ A,
                                                 const unsigned short* __restrict__ Wth,
                                                 const unsigned short* __restrict__ Wtl,
                                                 unsigned short* __restrict__ C, int M) {
    __shared__ unsigned short Xs[128 * 40];
    __shared__ unsigned short Wh[128 * 40];
    __shared__ unsigned short Wl[128 * 40];

    const int tid  = threadIdx.x;
    const int row0 = blockIdx.x * 128;
    const int trow  = tid >> 1;
    const int thalf = (tid & 1) * 16;

    int grow = row0 + trow;
    if (grow >= M) grow = M - 1;
    const float* xp = A + (long)grow * K + thalf;
    const unsigned short* wph = Wth + (long)trow * K + thalf;
    const unsigned short* wpl = Wtl + (long)trow * K + thalf;

    f32x4 acc[8][2];
    #pragma unroll
    for (int rf = 0; rf < 8; ++rf)
        #pragma unroll
        for (int cf = 0; cf < 2; ++cf)
            acc[rf][cf] = (f32x4){0.f, 0.f, 0.f, 0.f};

    float4 f0 = *(const float4*)(xp);
    float4 f1 = *(const float4*)(xp + 4);
    float4 f2 = *(const float4*)(xp + 8);
    float4 f3 = *(const float4*)(xp + 12);

    const int l   = tid & 63;
    const int wv  = tid >> 6;
    const int lr  = l & 15;
    const int lk8 = (l >> 4) * 8;

    for (int k0 = 0; k0 < K; k0 += 32) {
        uint4 wh0 = ((const uint4*)(wph + k0))[0];
        uint4 wh1 = ((const uint4*)(wph + k0))[1];
        uint4 wl0 = ((const uint4*)(wpl + k0))[0];
        uint4 wl1 = ((const uint4*)(wpl + k0))[1];
        unsigned short* xrow = &Xs[trow * 40 + thalf];
        *(uint4*)(xrow)     = make_uint4(pk2(f0.x, f0.y), pk2(f0.z, f0.w), pk2(f1.x, f1.y), pk2(f1.z, f1.w));
        *(uint4*)(xrow + 8) = make_uint4(pk2(f2.x, f2.y), pk2(f2.z, f2.w), pk2(f3.x, f3.y), pk2(f3.z, f3.w));
        *(uint4*)&Wh[trow * 40 + thalf]     = wh0;
        *(uint4*)&Wh[trow * 40 + thalf + 8] = wh1;
        *(uint4*)&Wl[trow * 40 + thalf]     = wl0;
        *(uint4*)&Wl[trow * 40 + thalf + 8] = wl1;
        __syncthreads();

        if (k0 + 32 < K) {
            f0 = *(const float4*)(xp + k0 + 32);
            f1 = *(const float4*)(xp + k0 + 36);
            f2 = *(const float4*)(xp + k0 + 40);
            f3 = *(const float4*)(xp + k0 + 44);
        }

        s16x8 xb[8], whf[2], wlf[2];
        #pragma unroll
        for (int rf = 0; rf < 8; ++rf)
            xb[rf] = *(const s16x8*)&Xs[(rf * 16 + lr) * 40 + lk8];
        #pragma unroll
        for (int cf = 0; cf < 2; ++cf) {
            whf[cf] = *(const s16x8*)&Wh[(wv * 32 + cf * 16 + lr) * 40 + lk8];
            wlf[cf] = *(const s16x8*)&Wl[(wv * 32 + cf * 16 + lr) * 40 + lk8];
        }
        #pragma unroll
        for (int rf = 0; rf < 8; ++rf)
            #pragma unroll
            for (int cf = 0; cf < 2; ++cf) {
                acc[rf][cf] = __builtin_amdgcn_mfma_f32_16x16x32_bf16(wlf[cf], xb[rf], acc[rf][cf], 0, 0, 0);
                acc[rf][cf] = __builtin_amdgcn_mfma_f32_16x16x32_bf16(whf[cf], xb[rf], acc[rf][cf], 0, 0, 0);
            }
        __syncthreads();
    }

    const int c4 = (l >> 4) * 4;
    #pragma unroll
    for (int rf = 0; rf < 8; ++rf) {
        int r = row0 + rf * 16 + lr;
        if (r < M) {
            #pragma unroll
            for (int cf = 0; cf < 2; ++cf) {
                int cb = wv * 32 + cf * 16 + c4;
                ushort4 v;
                v.x = f2bf(acc[rf][cf][0]);
                v.y = f2bf(acc[rf][cf][1]);
                v.z = f2bf(acc[rf][cf][2]);
                v.w = f2bf(acc[rf][cf][3]);
                *(ushort4*)(C + ((long)(cb >> 5) * N_NODES + r) * 32 + (cb & 31)) = v;
            }
        }
    }
}

// ---------------- chunked CSR gather: one 64B line per (node,chunk) ----------------
#define GATHER_BLOCKS 2048
template<int MODE>
__global__ __launch_bounds__(256, 8) void gather_chunk_kernel(
        const unsigned short* __restrict__ xlc, const float* __restrict__ dinv,
        const int* __restrict__ rowptr, const int2* __restrict__ csr,
        const float* __restrict__ bias, float* __restrict__ outbuf,
        const float* __restrict__ Wl, const int* __restrict__ batch,
        float* __restrict__ zsumR, int chunk) {
    const int lane = threadIdx.x & 63;
    const int es = lane >> 2;
    const int cl = lane & 3;
    const int c0 = cl * 8;
    const int gch = chunk * 32 + c0;

    const unsigned short* xc = xlc + (long)chunk * N_NODES * 32;

    const int wave   = blockIdx.x * 4 + (threadIdx.x >> 6);
    const int nwaves = GATHER_BLOCKS * 4;

    int node = wave;
    if (node >= N_NODES) return;
    int start = rowptr[node];
    int end   = rowptr[node + 1];

    for (; node < N_NODES; ) {
        int nxt = node + nwaves;
        int n_start = 0, n_end = 0;
        if (nxt < N_NODES) {
            n_start = rowptr[nxt];
            n_end   = rowptr[nxt + 1];
        }

        u16x8 sv = *(const u16x8*)(xc + (long)node * 32 + c0);

        float acc[8];
        #pragma unroll
        for (int j = 0; j < 8; ++j) acc[j] = 0.f;

        for (int eb = start; eb < end; eb += 16) {
            int e  = eb + es;
            int ec = (e < end) ? e : start;
            int2 cw = csr[ec];
            float w = (e < end) ? __int_as_float(cw.y) : 0.f;
            u16x8 r = *(const u16x8*)(xc + (long)cw.x * 32 + c0);
            #pragma unroll
            for (int j = 0; j < 8; ++j)
                acc[j] = fmaf(w, bf2f(r[j]), acc[j]);
        }

        #pragma unroll
        for (int j = 0; j < 8; ++j) {
            acc[j] += __shfl_xor(acc[j], 4);
            acc[j] += __shfl_xor(acc[j], 8);
            acc[j] += __shfl_xor(acc[j], 16);
            acc[j] += __shfl_xor(acc[j], 32);
        }

        float di = dinv[node];
        float w2 = di * di;
        const float4 bb0 = *(const float4*)(bias + gch);
        const float4 bb1 = *(const float4*)(bias + gch + 4);
        float bv[8] = {bb0.x, bb0.y, bb0.z, bb0.w, bb1.x, bb1.y, bb1.z, bb1.w};
        float s[8];
        #pragma unroll
        for (int j = 0; j < 8; ++j)
            s[j] = fmaxf(fmaf(w2, bf2f(sv[j]), acc[j]) + bv[j], 0.f);

        if (MODE == 0) {
            if (es == 0) {
                float* op = outbuf + (long)node * 128 + gch;
                *(float4*)(op)     = make_float4(s[0], s[1], s[2], s[3]);
                *(float4*)(op + 4) = make_float4(s[4], s[5], s[6], s[7]);
            }
        } else {
            const float4 wl0 = *(const float4*)(Wl + gch);
            const float4 wl1 = *(const float4*)(Wl + gch + 4);
            float z = s[0]*wl0.x + s[1]*wl0.y + s[2]*wl0.z + s[3]*wl0.w
                    + s[4]*wl1.x + s[5]*wl1.y + s[6]*wl1.z + s[7]*wl1.w;
            z += __shfl_xor(z, 1);
            z += __shfl_xor(z, 2);
            if (lane == 0)
                atomicAdd(&zsumR[(blockIdx.x & (ZREP - 1)) * N_GRAPHS + batch[node]], z);
        }

        node = nxt;
        start = n_start;
        end = n_end;
    }
}

__global__ void out_kernel(const float* __restrict__ zsumR, const float* __restrict__ cntg,
                           const float* __restrict__ bl, float* __restrict__ out) {
    int g = threadIdx.x;
    if (g < N_GRAPHS) {
        float z = 0.f;
        #pragma unroll
        for (int r = 0; r < ZREP; ++r) z += zsumR[r * N_GRAPHS + g];
        out[g] = z / fmaxf(cntg[g], 1.f) + bl[0];
    }
}

// ---------------- launch ----------------

extern "C" void kernel_launch(void* const* d_in, const int* in_sizes, int n_in,
                              void* d_out, int out_size, void* d_ws, size_t ws_size,
                              hipStream_t stream) {
    const float* x    = (const float*)d_in[0];
    const int*   ei   = (const int*)d_in[1];
    const int*   batch= (const int*)d_in[2];
    const float* W1   = (const float*)d_in[3];
    const float* b1   = (const float*)d_in[4];
    const float* W2   = (const float*)d_in[5];
    const float* b2   = (const float*)d_in[6];
    const float* Wl   = (const float*)d_in[7];
    const float* bl   = (const float*)d_in[8];
    float* out = (float*)d_out;

    // workspace layout (4B words)
    float* ws      = (float*)d_ws;
    float* dinv    = ws;                          // 50176
    float* zsumR   = ws + 50176;                  // 1024
    float* cntg    = ws + 51200;                  // 64
    int*   cnt_i   = (int*)(ws + 51264);          // 50176
    int*   rowptr  = (int*)(ws + 101440);         // 50176
    int2*  csr     = (int2*)(ws + 151616);        // 800000 int2
    unsigned short* xl16 = (unsigned short*)(ws + 1751616);  // [4][N][32] bf16
    float* h1      = ws + 1751616 + 3200000;      // 6.4M fp32 [node][128]
    unsigned short* w1h = (unsigned short*)(ws + 11351616);  // 98304 u16
    unsigned short* w1l = w1h + 98304;
    unsigned short* w2h = w1l + 98304;            // 16384 u16
    unsigned short* w2l = w2h + 16384;
    int* bsum = (int*)(w2l + 16384);              // 256
    int* boff = bsum + 256;                       // 256

    zero_int_kernel<<<128, 256, 0, stream>>>((int*)(ws + 50176), 1024 + 64 + 50176);

    hist_kernel<<<1024, 256, 0, stream>>>(ei, cnt_i);
    dinv_kernel<<<128, 256, 0, stream>>>(cnt_i, dinv);
    scanA_kernel<<<SCAN_BLOCKS, 256, 0, stream>>>(cnt_i, bsum);
    scanB_kernel<<<1, 256, 0, stream>>>(bsum, boff);
    scanC_kernel<<<SCAN_BLOCKS, 256, 0, stream>>>(cnt_i, boff, rowptr);
    fill_kernel<<<1024, 256, 0, stream>>>(ei, rowptr, cnt_i, dinv, csr);
    gcount_bs_kernel<<<1, 64, 0, stream>>>(batch, cntg);
    prep_w_kernel<<<448, 256, 0, stream>>>(W1, W2, w1h, w1l, w2h, w2l);

    // layer 1: xl1 = x@W1 (chunk-major bf16 via MFMA), per-chunk gather -> h1
    gemm_mfma<768><<<391, 256, 0, stream>>>(x, w1h, w1l, xl16, N_NODES);
    for (int c = 0; c < N_CHUNK; ++c)
        gather_chunk_kernel<0><<<GATHER_BLOCKS, 256, 0, stream>>>(
            xl16, dinv, rowptr, csr, b1, h1, nullptr, nullptr, nullptr, c);

    // layer 2: xl2 = h1@W2, per-chunk gather + pool
    gemm_mfma<128><<<391, 256, 0, stream>>>(h1, w2h, w2l, xl16, N_NODES);
    for (int c = 0; c < N_CHUNK; ++c)
        gather_chunk_kernel<1><<<GATHER_BLOCKS, 256, 0, stream>>>(
            xl16, dinv, rowptr, csr, b2, nullptr, Wl, batch, zsumR, c);

    out_kernel<<<1, 64, 0, stream>>>(zsumR, cntg, bl, out);
}

// Round 11
// 391.799 us; speedup vs baseline: 2.8077x; 1.0260x over previous
//
#include <hip/hip_runtime.h>

#define N_NODES  50000
#define N_EDGES  800000
#define N_GRAPHS 64
#define N_CHUNK  4          // 128 channels / 32
#define ZREP     16         // zsum replicas
#define SCAN_BLOCKS 196     // 196*256 = 50176

typedef unsigned short u16x8 __attribute__((ext_vector_type(8)));
typedef short s16x8 __attribute__((ext_vector_type(8)));
typedef float f32x4 __attribute__((ext_vector_type(4)));

__device__ __forceinline__ float bf2f(unsigned short h) {
    return __uint_as_float((unsigned)h << 16);
}
__device__ __forceinline__ unsigned short f2bf(float f) {
    unsigned u = __float_as_uint(f);
    unsigned r = (u + 0x7FFFu + ((u >> 16) & 1u)) >> 16;   // RNE
    return (unsigned short)r;
}
__device__ __forceinline__ unsigned pk2(float a, float b) {
    return (unsigned)f2bf(a) | ((unsigned)f2bf(b) << 16);
}

// ---------------- utility kernels ----------------

__global__ void zero_int_kernel(int* __restrict__ p, int n) {
    for (int i = blockIdx.x * blockDim.x + threadIdx.x; i < n; i += gridDim.x * blockDim.x)
        p[i] = 0;
}

__global__ void hist_kernel(const int* __restrict__ ei, int* __restrict__ cnt) {
    const int* dst = ei + N_EDGES;
    for (int e = blockIdx.x * blockDim.x + threadIdx.x; e < N_EDGES; e += gridDim.x * blockDim.x)
        atomicAdd(&cnt[dst[e]], 1);
}

__global__ void dinv_kernel(const int* __restrict__ cnt, float* __restrict__ dinv) {
    for (int i = blockIdx.x * blockDim.x + threadIdx.x; i < N_NODES; i += gridDim.x * blockDim.x)
        dinv[i] = rsqrtf((float)cnt[i] + 1.f);   // +1 self-loop
}

// ---- 3-phase multi-block exclusive scan of cnt[50176] -> rowptr ----
__global__ void scanA_kernel(const int* __restrict__ cnt, int* __restrict__ bsum) {
    __shared__ int wsum[4];
    int t = threadIdx.x;
    int v = cnt[blockIdx.x * 256 + t];
    #pragma unroll
    for (int off = 1; off < 64; off <<= 1) v += __shfl_xor(v, off);
    if ((t & 63) == 0) wsum[t >> 6] = v;
    __syncthreads();
    if (t == 0) bsum[blockIdx.x] = wsum[0] + wsum[1] + wsum[2] + wsum[3];
}

__global__ void scanB_kernel(const int* __restrict__ bsum, int* __restrict__ boff) {
    __shared__ int wsum[4];
    int t = threadIdx.x;
    int lane = t & 63, w = t >> 6;
    int v = (t < SCAN_BLOCKS) ? bsum[t] : 0;
    int s = v;
    #pragma unroll
    for (int off = 1; off < 64; off <<= 1) {
        int u = __shfl_up(s, off);
        if (lane >= off) s += u;
    }
    if (lane == 63) wsum[w] = s;
    __syncthreads();
    int wo = 0;
    for (int j = 0; j < w; ++j) wo += wsum[j];
    if (t < SCAN_BLOCKS) boff[t] = wo + s - v;   // exclusive
}

__global__ void scanC_kernel(int* __restrict__ cnt, const int* __restrict__ boff,
                             int* __restrict__ rowptr) {
    __shared__ int wsum[4];
    int t = threadIdx.x;
    int i = blockIdx.x * 256 + t;
    int lane = t & 63, w = t >> 6;
    int v = cnt[i];
    int s = v;
    #pragma unroll
    for (int off = 1; off < 64; off <<= 1) {
        int u = __shfl_up(s, off);
        if (lane >= off) s += u;
    }
    if (lane == 63) wsum[w] = s;
    __syncthreads();
    int wo = 0;
    for (int j = 0; j < w; ++j) wo += wsum[j];
    rowptr[i] = boff[blockIdx.x] + wo + s - v;   // i==N_NODES slot gets total E
    cnt[i] = 0;                                  // reset for fill pass
}

__global__ void fill_kernel(const int* __restrict__ ei, const int* __restrict__ rowptr,
                            int* __restrict__ fill, const float* __restrict__ dinv,
                            int2* __restrict__ csr) {
    const int* src = ei;
    const int* dst = ei + N_EDGES;
    for (int e = blockIdx.x * blockDim.x + threadIdx.x; e < N_EDGES; e += gridDim.x * blockDim.x) {
        int s = src[e], d = dst[e];
        int pos = rowptr[d] + atomicAdd(&fill[d], 1);
        csr[pos] = make_int2(s, __float_as_int(dinv[s] * dinv[d]));
    }
}

// batch is SORTED: per-graph count via binary search, no atomics
__global__ void gcount_bs_kernel(const int* __restrict__ batch, float* __restrict__ cntg) {
    int g = threadIdx.x;
    if (g >= N_GRAPHS) return;
    int lo = 0, hi = N_NODES;
    while (lo < hi) { int mid = (lo + hi) >> 1; if (batch[mid] < g) lo = mid + 1; else hi = mid; }
    int a = lo;
    lo = 0; hi = N_NODES;
    while (lo < hi) { int mid = (lo + hi) >> 1; if (batch[mid] < g + 1) lo = mid + 1; else hi = mid; }
    cntg[g] = (float)(lo - a);
}

// split W into hi/lo bf16, TRANSPOSED to [col][K]
__global__ void prep_w_kernel(const float* __restrict__ W1, const float* __restrict__ W2,
                              unsigned short* __restrict__ w1h, unsigned short* __restrict__ w1l,
                              unsigned short* __restrict__ w2h, unsigned short* __restrict__ w2l) {
    const int n1 = 768 * 128, n2 = 128 * 128;
    for (int i = blockIdx.x * blockDim.x + threadIdx.x; i < n1 + n2; i += gridDim.x * blockDim.x) {
        if (i < n1) {
            int k = i >> 7, c = i & 127;
            float w = W1[i];
            unsigned short hi = f2bf(w);
            unsigned short lo = f2bf(w - bf2f(hi));
            w1h[c * 768 + k] = hi;
            w1l[c * 768 + k] = lo;
        } else {
            int j = i - n1;
            int k = j >> 7, c = j & 127;
            float w = W2[j];
            unsigned short hi = f2bf(w);
            unsigned short lo = f2bf(w - bf2f(hi));
            w2h[c * 128 + k] = hi;
            w2l[c * 128 + k] = lo;
        }
    }
}

// ---------------- MFMA GEMM: C[M,128] = A[M,K] @ W[K,128] ----------------
// A fp32 (BF16A=false) or bf16 row-major (BF16A=true); W pre-split hi/lo bf16 [col][K].
// Two chained mfma per fragment => ~fp32-accurate W.
// Swapped operands (A-op = W^T, B-op = x); chunk-major ushort4 stores.
// Tile 128x128, BK=32, 4 waves; LDS rows padded to 40 u16.
template<int K, bool BF16A>
__global__ __launch_bounds__(256) void gemm_mfma(const void* __restrict__ Av,
                                                 const unsigned short* __restrict__ Wth,
                                                 const unsigned short* __restrict__ Wtl,
                                                 unsigned short* __restrict__ C, int M) {
    __shared__ unsigned short Xs[128 * 40];
    __shared__ unsigned short Wh[128 * 40];
    __shared__ unsigned short Wl[128 * 40];

    const int tid  = threadIdx.x;
    const int row0 = blockIdx.x * 128;
    const int trow  = tid >> 1;
    const int thalf = (tid & 1) * 16;

    int grow = row0 + trow;
    if (grow >= M) grow = M - 1;
    const float* xpf = (const float*)Av + (long)grow * K + thalf;
    const unsigned short* xpb = (const unsigned short*)Av + (long)grow * K + thalf;
    const unsigned short* wph = Wth + (long)trow * K + thalf;
    const unsigned short* wpl = Wtl + (long)trow * K + thalf;

    f32x4 acc[8][2];
    #pragma unroll
    for (int rf = 0; rf < 8; ++rf)
        #pragma unroll
        for (int cf = 0; cf < 2; ++cf)
            acc[rf][cf] = (f32x4){0.f, 0.f, 0.f, 0.f};

    // prefetch first X slice
    float4 f0, f1, f2, f3;
    uint4 b0, b1;
    if constexpr (!BF16A) {
        f0 = *(const float4*)(xpf);
        f1 = *(const float4*)(xpf + 4);
        f2 = *(const float4*)(xpf + 8);
        f3 = *(const float4*)(xpf + 12);
    } else {
        b0 = *(const uint4*)(xpb);
        b1 = *(const uint4*)(xpb + 8);
    }

    const int l   = tid & 63;
    const int wv  = tid >> 6;
    const int lr  = l & 15;
    const int lk8 = (l >> 4) * 8;

    for (int k0 = 0; k0 < K; k0 += 32) {
        uint4 wh0 = ((const uint4*)(wph + k0))[0];
        uint4 wh1 = ((const uint4*)(wph + k0))[1];
        uint4 wl0 = ((const uint4*)(wpl + k0))[0];
        uint4 wl1 = ((const uint4*)(wpl + k0))[1];
        unsigned short* xrow = &Xs[trow * 40 + thalf];
        if constexpr (!BF16A) {
            *(uint4*)(xrow)     = make_uint4(pk2(f0.x, f0.y), pk2(f0.z, f0.w), pk2(f1.x, f1.y), pk2(f1.z, f1.w));
            *(uint4*)(xrow + 8) = make_uint4(pk2(f2.x, f2.y), pk2(f2.z, f2.w), pk2(f3.x, f3.y), pk2(f3.z, f3.w));
        } else {
            *(uint4*)(xrow)     = b0;
            *(uint4*)(xrow + 8) = b1;
        }
        *(uint4*)&Wh[trow * 40 + thalf]     = wh0;
        *(uint4*)&Wh[trow * 40 + thalf + 8] = wh1;
        *(uint4*)&Wl[trow * 40 + thalf]     = wl0;
        *(uint4*)&Wl[trow * 40 + thalf + 8] = wl1;
        __syncthreads();

        if (k0 + 32 < K) {
            if constexpr (!BF16A) {
                f0 = *(const float4*)(xpf + k0 + 32);
                f1 = *(const float4*)(xpf + k0 + 36);
                f2 = *(const float4*)(xpf + k0 + 40);
                f3 = *(const float4*)(xpf + k0 + 44);
            } else {
                b0 = *(const uint4*)(xpb + k0 + 32);
                b1 = *(const uint4*)(xpb + k0 + 40);
            }
        }

        s16x8 xb[8], whf[2], wlf[2];
        #pragma unroll
        for (int rf = 0; rf < 8; ++rf)
            xb[rf] = *(const s16x8*)&Xs[(rf * 16 + lr) * 40 + lk8];
        #pragma unroll
        for (int cf = 0; cf < 2; ++cf) {
            whf[cf] = *(const s16x8*)&Wh[(wv * 32 + cf * 16 + lr) * 40 + lk8];
            wlf[cf] = *(const s16x8*)&Wl[(wv * 32 + cf * 16 + lr) * 40 + lk8];
        }
        #pragma unroll
        for (int rf = 0; rf < 8; ++rf)
            #pragma unroll
            for (int cf = 0; cf < 2; ++cf) {
                acc[rf][cf] = __builtin_amdgcn_mfma_f32_16x16x32_bf16(wlf[cf], xb[rf], acc[rf][cf], 0, 0, 0);
                acc[rf][cf] = __builtin_amdgcn_mfma_f32_16x16x32_bf16(whf[cf], xb[rf], acc[rf][cf], 0, 0, 0);
            }
        __syncthreads();
    }

    const int c4 = (l >> 4) * 4;
    #pragma unroll
    for (int rf = 0; rf < 8; ++rf) {
        int r = row0 + rf * 16 + lr;
        if (r < M) {
            #pragma unroll
            for (int cf = 0; cf < 2; ++cf) {
                int cb = wv * 32 + cf * 16 + c4;
                ushort4 v;
                v.x = f2bf(acc[rf][cf][0]);
                v.y = f2bf(acc[rf][cf][1]);
                v.z = f2bf(acc[rf][cf][2]);
                v.w = f2bf(acc[rf][cf][3]);
                *(ushort4*)(C + ((long)(cb >> 5) * N_NODES + r) * 32 + (cb & 31)) = v;
            }
        }
    }
}

// ---------------- chunked CSR gather with 1-deep cross-node prefetch ----------------
// Per pass (chunk): random working set = 3.2 MB -> per-XCD L2 resident.
// Lane layout: es = lane>>2 (16 edge slots), cl = lane&3 (8 channels each).
// While node n computes, node n+1's {rowptr, first-16 csr, self-line} are in flight.
// MODE 0: outbuf (bf16 [node][128]) = relu(agg + bias)   -- bit-identical to
//         fp32 store + later rounding (GEMM2 rounds at staging anyway).
// MODE 1: z = dot(relu(agg+bias), Wl_chunk); zsumR[rep][batch] += z
#define GATHER_BLOCKS 2048
template<int MODE>
__global__ __launch_bounds__(256, 8) void gather_chunk_kernel(
        const unsigned short* __restrict__ xlc, const float* __restrict__ dinv,
        const int* __restrict__ rowptr, const int2* __restrict__ csr,
        const float* __restrict__ bias, unsigned short* __restrict__ outbuf,
        const float* __restrict__ Wl, const int* __restrict__ batch,
        float* __restrict__ zsumR, int chunk) {
    const int lane = threadIdx.x & 63;
    const int es = lane >> 2;       // edge slot 0..15
    const int cl = lane & 3;        // channel lane
    const int c0 = cl * 8;          // channel offset within chunk
    const int gch = chunk * 32 + c0;

    const unsigned short* xc = xlc + (long)chunk * N_NODES * 32;

    const int wave   = blockIdx.x * 4 + (threadIdx.x >> 6);
    const int nwaves = GATHER_BLOCKS * 4;

    int node = wave;
    if (node >= N_NODES) return;
    int start = rowptr[node];
    int end   = rowptr[node + 1];
    int pe = start + es; pe = (pe < N_EDGES) ? pe : N_EDGES - 1;
    int2 cpre = csr[pe];                                   // first-16 csr prefetch
    u16x8 sv = *(const u16x8*)(xc + (long)node * 32 + c0); // self-line prefetch

    while (true) {
        // ---- issue next node's prefetches (overlap with this node's compute) ----
        int nxt = node + nwaves;
        bool has_nxt = nxt < N_NODES;
        int cn = has_nxt ? nxt : node;
        int n_start = rowptr[cn];
        int n_end   = rowptr[cn + 1];
        u16x8 n_sv = *(const u16x8*)(xc + (long)cn * 32 + c0);  // independent: issues now
        int npe = n_start + es; npe = (npe < N_EDGES) ? npe : N_EDGES - 1;
        int2 n_cpre = csr[npe];                                  // chained after rowptr

        // ---- this node's aggregation ----
        float acc[8];
        #pragma unroll
        for (int j = 0; j < 8; ++j) acc[j] = 0.f;

        {   // first 16 edges from prefetched metadata
            int e = start + es;
            float w = (e < end) ? __int_as_float(cpre.y) : 0.f;
            u16x8 r = *(const u16x8*)(xc + (long)cpre.x * 32 + c0);
            #pragma unroll
            for (int j = 0; j < 8; ++j)
                acc[j] = fmaf(w, bf2f(r[j]), acc[j]);
        }
        for (int eb = start + 16; eb < end; eb += 16) {
            int e  = eb + es;
            int ec = (e < end) ? e : start;
            int2 cw = csr[ec];
            float w = (e < end) ? __int_as_float(cw.y) : 0.f;
            u16x8 r = *(const u16x8*)(xc + (long)cw.x * 32 + c0);
            #pragma unroll
            for (int j = 0; j < 8; ++j)
                acc[j] = fmaf(w, bf2f(r[j]), acc[j]);
        }

        // reduce across the 16 edge slots (lane bits 2..5)
        #pragma unroll
        for (int j = 0; j < 8; ++j) {
            acc[j] += __shfl_xor(acc[j], 4);
            acc[j] += __shfl_xor(acc[j], 8);
            acc[j] += __shfl_xor(acc[j], 16);
            acc[j] += __shfl_xor(acc[j], 32);
        }

        // self-loop + bias + relu
        float di = dinv[node];
        float w2 = di * di;
        const float4 bb0 = *(const float4*)(bias + gch);
        const float4 bb1 = *(const float4*)(bias + gch + 4);
        float bv[8] = {bb0.x, bb0.y, bb0.z, bb0.w, bb1.x, bb1.y, bb1.z, bb1.w};
        float s[8];
        #pragma unroll
        for (int j = 0; j < 8; ++j)
            s[j] = fmaxf(fmaf(w2, bf2f(sv[j]), acc[j]) + bv[j], 0.f);

        if (MODE == 0) {
            if (es == 0) {   // lanes 0..3 cover the chunk's 32 channels
                u16x8 o;
                #pragma unroll
                for (int j = 0; j < 8; ++j) o[j] = f2bf(s[j]);
                *(u16x8*)(outbuf + (long)node * 128 + gch) = o;
            }
        } else {
            const float4 wl0 = *(const float4*)(Wl + gch);
            const float4 wl1 = *(const float4*)(Wl + gch + 4);
            float z = s[0]*wl0.x + s[1]*wl0.y + s[2]*wl0.z + s[3]*wl0.w
                    + s[4]*wl1.x + s[5]*wl1.y + s[6]*wl1.z + s[7]*wl1.w;
            z += __shfl_xor(z, 1);
            z += __shfl_xor(z, 2);
            if (lane == 0)
                atomicAdd(&zsumR[(blockIdx.x & (ZREP - 1)) * N_GRAPHS + batch[node]], z);
        }

        if (!has_nxt) break;
        node = nxt; start = n_start; end = n_end; cpre = n_cpre; sv = n_sv;
    }
}

__global__ void out_kernel(const float* __restrict__ zsumR, const float* __restrict__ cntg,
                           const float* __restrict__ bl, float* __restrict__ out) {
    int g = threadIdx.x;
    if (g < N_GRAPHS) {
        float z = 0.f;
        #pragma unroll
        for (int r = 0; r < ZREP; ++r) z += zsumR[r * N_GRAPHS + g];
        out[g] = z / fmaxf(cntg[g], 1.f) + bl[0];
    }
}

// ---------------- launch ----------------

extern "C" void kernel_launch(void* const* d_in, const int* in_sizes, int n_in,
                              void* d_out, int out_size, void* d_ws, size_t ws_size,
                              hipStream_t stream) {
    const float* x    = (const float*)d_in[0];
    const int*   ei   = (const int*)d_in[1];
    const int*   batch= (const int*)d_in[2];
    const float* W1   = (const float*)d_in[3];
    const float* b1   = (const float*)d_in[4];
    const float* W2   = (const float*)d_in[5];
    const float* b2   = (const float*)d_in[6];
    const float* Wl   = (const float*)d_in[7];
    const float* bl   = (const float*)d_in[8];
    float* out = (float*)d_out;

    // workspace layout (4B words)
    float* ws      = (float*)d_ws;
    float* dinv    = ws;                          // 50176
    float* zsumR   = ws + 50176;                  // 1024
    float* cntg    = ws + 51200;                  // 64
    int*   cnt_i   = (int*)(ws + 51264);          // 50176
    int*   rowptr  = (int*)(ws + 101440);         // 50176
    int2*  csr     = (int2*)(ws + 151616);        // 800000 int2
    unsigned short* xl16 = (unsigned short*)(ws + 1751616);  // [4][N][32] bf16
    unsigned short* h1   = (unsigned short*)(ws + 1751616 + 3200000);  // [N][128] bf16
    unsigned short* w1h = (unsigned short*)(ws + 11351616);  // 98304 u16
    unsigned short* w1l = w1h + 98304;
    unsigned short* w2h = w1l + 98304;            // 16384 u16
    unsigned short* w2l = w2h + 16384;
    int* bsum = (int*)(w2l + 16384);              // 256
    int* boff = bsum + 256;                       // 256

    zero_int_kernel<<<128, 256, 0, stream>>>((int*)(ws + 50176), 1024 + 64 + 50176);

    hist_kernel<<<1024, 256, 0, stream>>>(ei, cnt_i);
    dinv_kernel<<<128, 256, 0, stream>>>(cnt_i, dinv);
    scanA_kernel<<<SCAN_BLOCKS, 256, 0, stream>>>(cnt_i, bsum);
    scanB_kernel<<<1, 256, 0, stream>>>(bsum, boff);
    scanC_kernel<<<SCAN_BLOCKS, 256, 0, stream>>>(cnt_i, boff, rowptr);
    fill_kernel<<<1024, 256, 0, stream>>>(ei, rowptr, cnt_i, dinv, csr);
    gcount_bs_kernel<<<1, 64, 0, stream>>>(batch, cntg);
    prep_w_kernel<<<448, 256, 0, stream>>>(W1, W2, w1h, w1l, w2h, w2l);

    // layer 1: xl1 = x@W1 (chunk-major bf16 via MFMA), per-chunk gather -> h1 (bf16)
    gemm_mfma<768, false><<<391, 256, 0, stream>>>(x, w1h, w1l, xl16, N_NODES);
    for (int c = 0; c < N_CHUNK; ++c)
        gather_chunk_kernel<0><<<GATHER_BLOCKS, 256, 0, stream>>>(
            xl16, dinv, rowptr, csr, b1, h1, nullptr, nullptr, nullptr, c);

    // layer 2: xl2 = h1@W2 (bf16 in), per-chunk gather + pool
    gemm_mfma<128, true><<<391, 256, 0, stream>>>(h1, w2h, w2l, xl16, N_NODES);
    for (int c = 0; c < N_CHUNK; ++c)
        gather_chunk_kernel<1><<<GATHER_BLOCKS, 256, 0, stream>>>(
            xl16, dinv, rowptr, csr, b2, nullptr, Wl, batch, zsumR, c);

    out_kernel<<<1, 64, 0, stream>>>(zsumR, cntg, bl, out);
}

// Round 12
// 387.563 us; speedup vs baseline: 2.8384x; 1.0109x over previous
//
#include <hip/hip_runtime.h>

#define N_NODES  50000
#define N_EDGES  800000
#define N_GRAPHS 64
#define N_CHUNK  4          // 128 channels / 32
#define ZREP     16         // zsum replicas
#define SCAN_BLOCKS 196     // 196*256 = 50176

typedef unsigned short u16x8 __attribute__((ext_vector_type(8)));
typedef short s16x8 __attribute__((ext_vector_type(8)));
typedef float f32x4 __attribute__((ext_vector_type(4)));

__device__ __forceinline__ float bf2f(unsigned short h) {
    return __uint_as_float((unsigned)h << 16);
}
__device__ __forceinline__ unsigned short f2bf(float f) {
    unsigned u = __float_as_uint(f);
    unsigned r = (u + 0x7FFFu + ((u >> 16) & 1u)) >> 16;   // RNE
    return (unsigned short)r;
}
__device__ __forceinline__ unsigned pk2(float a, float b) {
    return (unsigned)f2bf(a) | ((unsigned)f2bf(b) << 16);
}

// ---------------- utility kernels ----------------

__global__ void zero_int_kernel(int* __restrict__ p, int n) {
    for (int i = blockIdx.x * blockDim.x + threadIdx.x; i < n; i += gridDim.x * blockDim.x)
        p[i] = 0;
}

__global__ void hist_kernel(const int* __restrict__ ei, int* __restrict__ cnt) {
    const int* dst = ei + N_EDGES;
    for (int e = blockIdx.x * blockDim.x + threadIdx.x; e < N_EDGES; e += gridDim.x * blockDim.x)
        atomicAdd(&cnt[dst[e]], 1);
}

// ---- 3-phase multi-block exclusive scan of cnt[50176] -> rowptr (A also emits dinv) ----
__global__ void scanA_kernel(const int* __restrict__ cnt, int* __restrict__ bsum,
                             float* __restrict__ dinv) {
    __shared__ int wsum[4];
    int t = threadIdx.x;
    int i = blockIdx.x * 256 + t;
    int v = cnt[i];
    if (i < N_NODES) dinv[i] = rsqrtf((float)v + 1.f);   // +1 self-loop
    int s = v;
    #pragma unroll
    for (int off = 1; off < 64; off <<= 1) s += __shfl_xor(s, off);
    if ((t & 63) == 0) wsum[t >> 6] = s;
    __syncthreads();
    if (t == 0) bsum[blockIdx.x] = wsum[0] + wsum[1] + wsum[2] + wsum[3];
}

__global__ void scanB_kernel(const int* __restrict__ bsum, int* __restrict__ boff) {
    __shared__ int wsum[4];
    int t = threadIdx.x;
    int lane = t & 63, w = t >> 6;
    int v = (t < SCAN_BLOCKS) ? bsum[t] : 0;
    int s = v;
    #pragma unroll
    for (int off = 1; off < 64; off <<= 1) {
        int u = __shfl_up(s, off);
        if (lane >= off) s += u;
    }
    if (lane == 63) wsum[w] = s;
    __syncthreads();
    int wo = 0;
    for (int j = 0; j < w; ++j) wo += wsum[j];
    if (t < SCAN_BLOCKS) boff[t] = wo + s - v;   // exclusive
}

__global__ void scanC_kernel(int* __restrict__ cnt, const int* __restrict__ boff,
                             int* __restrict__ rowptr) {
    __shared__ int wsum[4];
    int t = threadIdx.x;
    int i = blockIdx.x * 256 + t;
    int lane = t & 63, w = t >> 6;
    int v = cnt[i];
    int s = v;
    #pragma unroll
    for (int off = 1; off < 64; off <<= 1) {
        int u = __shfl_up(s, off);
        if (lane >= off) s += u;
    }
    if (lane == 63) wsum[w] = s;
    __syncthreads();
    int wo = 0;
    for (int j = 0; j < w; ++j) wo += wsum[j];
    rowptr[i] = boff[blockIdx.x] + wo + s - v;   // i==N_NODES slot gets total E
    cnt[i] = 0;                                  // reset for fill pass
}

__global__ void fill_kernel(const int* __restrict__ ei, const int* __restrict__ rowptr,
                            int* __restrict__ fill, const float* __restrict__ dinv,
                            int2* __restrict__ csr) {
    const int* src = ei;
    const int* dst = ei + N_EDGES;
    for (int e = blockIdx.x * blockDim.x + threadIdx.x; e < N_EDGES; e += gridDim.x * blockDim.x) {
        int s = src[e], d = dst[e];
        int pos = rowptr[d] + atomicAdd(&fill[d], 1);
        csr[pos] = make_int2(s, __float_as_int(dinv[s] * dinv[d]));
    }
}

// batch is SORTED: per-graph count via binary search; also zeroes zsumR
__global__ void gcount_bs_kernel(const int* __restrict__ batch, float* __restrict__ cntg,
                                 float* __restrict__ zsumR) {
    int g = threadIdx.x;
    if (g >= N_GRAPHS) return;
    #pragma unroll
    for (int r = 0; r < ZREP; ++r) zsumR[r * N_GRAPHS + g] = 0.f;
    int lo = 0, hi = N_NODES;
    while (lo < hi) { int mid = (lo + hi) >> 1; if (batch[mid] < g) lo = mid + 1; else hi = mid; }
    int a = lo;
    lo = 0; hi = N_NODES;
    while (lo < hi) { int mid = (lo + hi) >> 1; if (batch[mid] < g + 1) lo = mid + 1; else hi = mid; }
    cntg[g] = (float)(lo - a);
}

// split W into hi/lo bf16, TRANSPOSED to [col][K]
__global__ void prep_w_kernel(const float* __restrict__ W1, const float* __restrict__ W2,
                              unsigned short* __restrict__ w1h, unsigned short* __restrict__ w1l,
                              unsigned short* __restrict__ w2h, unsigned short* __restrict__ w2l) {
    const int n1 = 768 * 128, n2 = 128 * 128;
    for (int i = blockIdx.x * blockDim.x + threadIdx.x; i < n1 + n2; i += gridDim.x * blockDim.x) {
        if (i < n1) {
            int k = i >> 7, c = i & 127;
            float w = W1[i];
            unsigned short hi = f2bf(w);
            unsigned short lo = f2bf(w - bf2f(hi));
            w1h[c * 768 + k] = hi;
            w1l[c * 768 + k] = lo;
        } else {
            int j = i - n1;
            int k = j >> 7, c = j & 127;
            float w = W2[j];
            unsigned short hi = f2bf(w);
            unsigned short lo = f2bf(w - bf2f(hi));
            w2h[c * 128 + k] = hi;
            w2l[c * 128 + k] = lo;
        }
    }
}

// ---------------- MFMA GEMM: C[M,128] = A[M,K] @ W[K,128] ----------------
// A fp32 (BF16A=false) or bf16 row-major (BF16A=true); W pre-split hi/lo bf16 [col][K].
// Two chained mfma per fragment => ~fp32-accurate W.
// Swapped operands (A-op = W^T, B-op = x); chunk-major ushort4 stores.
// Tile 128x128, BK=32, 4 waves; LDS rows padded to 40 u16.
template<int K, bool BF16A>
__global__ __launch_bounds__(256) void gemm_mfma(const void* __restrict__ Av,
                                                 const unsigned short* __restrict__ Wth,
                                                 const unsigned short* __restrict__ Wtl,
                                                 unsigned short* __restrict__ C, int M) {
    __shared__ unsigned short Xs[128 * 40];
    __shared__ unsigned short Wh[128 * 40];
    __shared__ unsigned short Wl[128 * 40];

    const int tid  = threadIdx.x;
    const int row0 = blockIdx.x * 128;
    const int trow  = tid >> 1;
    const int thalf = (tid & 1) * 16;

    int grow = row0 + trow;
    if (grow >= M) grow = M - 1;
    const float* xpf = (const float*)Av + (long)grow * K + thalf;
    const unsigned short* xpb = (const unsigned short*)Av + (long)grow * K + thalf;
    const unsigned short* wph = Wth + (long)trow * K + thalf;
    const unsigned short* wpl = Wtl + (long)trow * K + thalf;

    f32x4 acc[8][2];
    #pragma unroll
    for (int rf = 0; rf < 8; ++rf)
        #pragma unroll
        for (int cf = 0; cf < 2; ++cf)
            acc[rf][cf] = (f32x4){0.f, 0.f, 0.f, 0.f};

    float4 f0, f1, f2, f3;
    uint4 b0, b1;
    if constexpr (!BF16A) {
        f0 = *(const float4*)(xpf);
        f1 = *(const float4*)(xpf + 4);
        f2 = *(const float4*)(xpf + 8);
        f3 = *(const float4*)(xpf + 12);
    } else {
        b0 = *(const uint4*)(xpb);
        b1 = *(const uint4*)(xpb + 8);
    }

    const int l   = tid & 63;
    const int wv  = tid >> 6;
    const int lr  = l & 15;
    const int lk8 = (l >> 4) * 8;

    for (int k0 = 0; k0 < K; k0 += 32) {
        uint4 wh0 = ((const uint4*)(wph + k0))[0];
        uint4 wh1 = ((const uint4*)(wph + k0))[1];
        uint4 wl0 = ((const uint4*)(wpl + k0))[0];
        uint4 wl1 = ((const uint4*)(wpl + k0))[1];
        unsigned short* xrow = &Xs[trow * 40 + thalf];
        if constexpr (!BF16A) {
            *(uint4*)(xrow)     = make_uint4(pk2(f0.x, f0.y), pk2(f0.z, f0.w), pk2(f1.x, f1.y), pk2(f1.z, f1.w));
            *(uint4*)(xrow + 8) = make_uint4(pk2(f2.x, f2.y), pk2(f2.z, f2.w), pk2(f3.x, f3.y), pk2(f3.z, f3.w));
        } else {
            *(uint4*)(xrow)     = b0;
            *(uint4*)(xrow + 8) = b1;
        }
        *(uint4*)&Wh[trow * 40 + thalf]     = wh0;
        *(uint4*)&Wh[trow * 40 + thalf + 8] = wh1;
        *(uint4*)&Wl[trow * 40 + thalf]     = wl0;
        *(uint4*)&Wl[trow * 40 + thalf + 8] = wl1;
        __syncthreads();

        if (k0 + 32 < K) {
            if constexpr (!BF16A) {
                f0 = *(const float4*)(xpf + k0 + 32);
                f1 = *(const float4*)(xpf + k0 + 36);
                f2 = *(const float4*)(xpf + k0 + 40);
                f3 = *(const float4*)(xpf + k0 + 44);
            } else {
                b0 = *(const uint4*)(xpb + k0 + 32);
                b1 = *(const uint4*)(xpb + k0 + 40);
            }
        }

        s16x8 xb[8], whf[2], wlf[2];
        #pragma unroll
        for (int rf = 0; rf < 8; ++rf)
            xb[rf] = *(const s16x8*)&Xs[(rf * 16 + lr) * 40 + lk8];
        #pragma unroll
        for (int cf = 0; cf < 2; ++cf) {
            whf[cf] = *(const s16x8*)&Wh[(wv * 32 + cf * 16 + lr) * 40 + lk8];
            wlf[cf] = *(const s16x8*)&Wl[(wv * 32 + cf * 16 + lr) * 40 + lk8];
        }
        #pragma unroll
        for (int rf = 0; rf < 8; ++rf)
            #pragma unroll
            for (int cf = 0; cf < 2; ++cf) {
                acc[rf][cf] = __builtin_amdgcn_mfma_f32_16x16x32_bf16(wlf[cf], xb[rf], acc[rf][cf], 0, 0, 0);
                acc[rf][cf] = __builtin_amdgcn_mfma_f32_16x16x32_bf16(whf[cf], xb[rf], acc[rf][cf], 0, 0, 0);
            }
        __syncthreads();
    }

    const int c4 = (l >> 4) * 4;
    #pragma unroll
    for (int rf = 0; rf < 8; ++rf) {
        int r = row0 + rf * 16 + lr;
        if (r < M) {
            #pragma unroll
            for (int cf = 0; cf < 2; ++cf) {
                int cb = wv * 32 + cf * 16 + c4;
                ushort4 v;
                v.x = f2bf(acc[rf][cf][0]);
                v.y = f2bf(acc[rf][cf][1]);
                v.z = f2bf(acc[rf][cf][2]);
                v.w = f2bf(acc[rf][cf][3]);
                *(ushort4*)(C + ((long)(cb >> 5) * N_NODES + r) * 32 + (cb & 31)) = v;
            }
        }
    }
}

// ---------------- merged chunked CSR gather: XCD-pinned chunks ----------------
// One dispatch covers all 4 chunks: blocks on XCD k (blockIdx&7) process chunk k&3,
// so each XCD's 4MB L2 keeps its 3.2MB chunk resident the whole dispatch.
// Per chunk: 512 blocks = 2048 waves, ~24 nodes/wave (good prefetch amortization).
// Lane layout: es = lane>>2 (16 edge slots), cl = lane&3 (8 channels each).
// 1-deep cross-node prefetch of {rowptr, first-16 csr, self-line}.
// MODE 0: outbuf (bf16 [node][128]) = relu(agg + bias)
// MODE 1: z = dot(relu(agg+bias), Wl_chunk); zsumR[rep][batch] += z
#define GATHER_BLOCKS 2048
template<int MODE>
__global__ __launch_bounds__(256, 8) void gather_all_kernel(
        const unsigned short* __restrict__ xlc, const float* __restrict__ dinv,
        const int* __restrict__ rowptr, const int2* __restrict__ csr,
        const float* __restrict__ bias, unsigned short* __restrict__ outbuf,
        const float* __restrict__ Wl, const int* __restrict__ batch,
        float* __restrict__ zsumR) {
    const int lane = threadIdx.x & 63;
    const int es = lane >> 2;       // edge slot 0..15
    const int cl = lane & 3;        // channel lane
    const int c0 = cl * 8;          // channel offset within chunk

    const int grp   = blockIdx.x & 7;            // ~XCD id (round-robin dispatch)
    const int chunk = grp & 3;
    const int gch   = chunk * 32 + c0;
    const unsigned short* xc = xlc + (long)chunk * N_NODES * 32;

    const int cblk   = (blockIdx.x >> 3) + (grp >> 2) * 256;   // 0..511 within chunk
    const int wave   = cblk * 4 + (threadIdx.x >> 6);          // 0..2047
    const int nwaves = 2048;

    int node = wave;                      // wave < 2048 <= N_NODES always
    int start = rowptr[node];
    int end   = rowptr[node + 1];
    int pe = start + es; pe = (pe < N_EDGES) ? pe : N_EDGES - 1;
    int2 cpre = csr[pe];                                   // first-16 csr prefetch
    u16x8 sv = *(const u16x8*)(xc + (long)node * 32 + c0); // self-line prefetch

    while (true) {
        // ---- issue next node's prefetches (overlap with this node's compute) ----
        int nxt = node + nwaves;
        bool has_nxt = nxt < N_NODES;
        int cn = has_nxt ? nxt : node;
        int n_start = rowptr[cn];
        int n_end   = rowptr[cn + 1];
        u16x8 n_sv = *(const u16x8*)(xc + (long)cn * 32 + c0);  // independent: issues now
        int npe = n_start + es; npe = (npe < N_EDGES) ? npe : N_EDGES - 1;
        int2 n_cpre = csr[npe];                                  // chained after rowptr

        // ---- this node's aggregation ----
        float acc[8];
        #pragma unroll
        for (int j = 0; j < 8; ++j) acc[j] = 0.f;

        {   // first 16 edges from prefetched metadata
            int e = start + es;
            float w = (e < end) ? __int_as_float(cpre.y) : 0.f;
            u16x8 r = *(const u16x8*)(xc + (long)cpre.x * 32 + c0);
            #pragma unroll
            for (int j = 0; j < 8; ++j)
                acc[j] = fmaf(w, bf2f(r[j]), acc[j]);
        }
        for (int eb = start + 16; eb < end; eb += 16) {
            int e  = eb + es;
            int ec = (e < end) ? e : start;
            int2 cw = csr[ec];
            float w = (e < end) ? __int_as_float(cw.y) : 0.f;
            u16x8 r = *(const u16x8*)(xc + (long)cw.x * 32 + c0);
            #pragma unroll
            for (int j = 0; j < 8; ++j)
                acc[j] = fmaf(w, bf2f(r[j]), acc[j]);
        }

        // reduce across the 16 edge slots (lane bits 2..5)
        #pragma unroll
        for (int j = 0; j < 8; ++j) {
            acc[j] += __shfl_xor(acc[j], 4);
            acc[j] += __shfl_xor(acc[j], 8);
            acc[j] += __shfl_xor(acc[j], 16);
            acc[j] += __shfl_xor(acc[j], 32);
        }

        // self-loop + bias + relu
        float di = dinv[node];
        float w2 = di * di;
        const float4 bb0 = *(const float4*)(bias + gch);
        const float4 bb1 = *(const float4*)(bias + gch + 4);
        float bv[8] = {bb0.x, bb0.y, bb0.z, bb0.w, bb1.x, bb1.y, bb1.z, bb1.w};
        float s[8];
        #pragma unroll
        for (int j = 0; j < 8; ++j)
            s[j] = fmaxf(fmaf(w2, bf2f(sv[j]), acc[j]) + bv[j], 0.f);

        if (MODE == 0) {
            if (es == 0) {   // lanes 0..3 cover the chunk's 32 channels
                u16x8 o;
                #pragma unroll
                for (int j = 0; j < 8; ++j) o[j] = f2bf(s[j]);
                *(u16x8*)(outbuf + (long)node * 128 + gch) = o;
            }
        } else {
            const float4 wl0 = *(const float4*)(Wl + gch);
            const float4 wl1 = *(const float4*)(Wl + gch + 4);
            float z = s[0]*wl0.x + s[1]*wl0.y + s[2]*wl0.z + s[3]*wl0.w
                    + s[4]*wl1.x + s[5]*wl1.y + s[6]*wl1.z + s[7]*wl1.w;
            z += __shfl_xor(z, 1);
            z += __shfl_xor(z, 2);
            if (lane == 0)
                atomicAdd(&zsumR[(blockIdx.x & (ZREP - 1)) * N_GRAPHS + batch[node]], z);
        }

        if (!has_nxt) break;
        node = nxt; start = n_start; end = n_end; cpre = n_cpre; sv = n_sv;
    }
}

__global__ void out_kernel(const float* __restrict__ zsumR, const float* __restrict__ cntg,
                           const float* __restrict__ bl, float* __restrict__ out) {
    int g = threadIdx.x;
    if (g < N_GRAPHS) {
        float z = 0.f;
        #pragma unroll
        for (int r = 0; r < ZREP; ++r) z += zsumR[r * N_GRAPHS + g];
        out[g] = z / fmaxf(cntg[g], 1.f) + bl[0];
    }
}

// ---------------- launch ----------------

extern "C" void kernel_launch(void* const* d_in, const int* in_sizes, int n_in,
                              void* d_out, int out_size, void* d_ws, size_t ws_size,
                              hipStream_t stream) {
    const float* x    = (const float*)d_in[0];
    const int*   ei   = (const int*)d_in[1];
    const int*   batch= (const int*)d_in[2];
    const float* W1   = (const float*)d_in[3];
    const float* b1   = (const float*)d_in[4];
    const float* W2   = (const float*)d_in[5];
    const float* b2   = (const float*)d_in[6];
    const float* Wl   = (const float*)d_in[7];
    const float* bl   = (const float*)d_in[8];
    float* out = (float*)d_out;

    // workspace layout (4B words)
    float* ws      = (float*)d_ws;
    float* dinv    = ws;                          // 50176
    float* zsumR   = ws + 50176;                  // 1024
    float* cntg    = ws + 51200;                  // 64
    int*   cnt_i   = (int*)(ws + 51264);          // 50176
    int*   rowptr  = (int*)(ws + 101440);         // 50176
    int2*  csr     = (int2*)(ws + 151616);        // 800000 int2
    unsigned short* xl16 = (unsigned short*)(ws + 1751616);  // [4][N][32] bf16
    unsigned short* h1   = (unsigned short*)(ws + 1751616 + 3200000);  // [N][128] bf16
    unsigned short* w1h = (unsigned short*)(ws + 11351616);  // 98304 u16
    unsigned short* w1l = w1h + 98304;
    unsigned short* w2h = w1l + 98304;            // 16384 u16
    unsigned short* w2l = w2h + 16384;
    int* bsum = (int*)(w2l + 16384);              // 256
    int* boff = bsum + 256;                       // 256

    zero_int_kernel<<<128, 256, 0, stream>>>(cnt_i, 50176);

    hist_kernel<<<1024, 256, 0, stream>>>(ei, cnt_i);
    scanA_kernel<<<SCAN_BLOCKS, 256, 0, stream>>>(cnt_i, bsum, dinv);
    scanB_kernel<<<1, 256, 0, stream>>>(bsum, boff);
    scanC_kernel<<<SCAN_BLOCKS, 256, 0, stream>>>(cnt_i, boff, rowptr);
    fill_kernel<<<1024, 256, 0, stream>>>(ei, rowptr, cnt_i, dinv, csr);
    gcount_bs_kernel<<<1, 64, 0, stream>>>(batch, cntg, zsumR);
    prep_w_kernel<<<448, 256, 0, stream>>>(W1, W2, w1h, w1l, w2h, w2l);

    // layer 1: xl1 = x@W1 (chunk-major bf16 via MFMA), merged gather -> h1 (bf16)
    gemm_mfma<768, false><<<391, 256, 0, stream>>>(x, w1h, w1l, xl16, N_NODES);
    gather_all_kernel<0><<<GATHER_BLOCKS, 256, 0, stream>>>(
        xl16, dinv, rowptr, csr, b1, h1, nullptr, nullptr, nullptr);

    // layer 2: xl2 = h1@W2 (bf16 in), merged gather + pool
    gemm_mfma<128, true><<<391, 256, 0, stream>>>(h1, w2h, w2l, xl16, N_NODES);
    gather_all_kernel<1><<<GATHER_BLOCKS, 256, 0, stream>>>(
        xl16, dinv, rowptr, csr, b2, nullptr, Wl, batch, zsumR);

    out_kernel<<<1, 64, 0, stream>>>(zsumR, cntg, bl, out);
}